// Round 4
// baseline (95.302 us; speedup 1.0000x reference)
//
#include <hip/hip_runtime.h>
#include <stdint.h>

#define N_PROP 2000
#define NCLS 80
#define MAXPC 100
#define MAXIMG 300
#define NFLAT (NCLS*MAXPC)   // 8000
#define MAXNB 32
#define CAP 768              // max compacted candidates (tie-path bound: 692)
#define TOUT 304             // max t ever requested (300)
#define FKEY_NEGINF 0x007FFFFFu

#define ST_UNDEC 0
#define ST_KEPT 1
#define ST_SUPP 2

// persistent device scratch (fully rewritten every launch -> deterministic)
__device__ float4   g_boxes[N_PROP];
__device__ uint32_t g_adj[N_PROP * 64];     // bitset rows (self-bit excluded)
__device__ int      g_deg[N_PROP];
__device__ int      g_nbr[N_PROP * MAXNB];  // neighbor lists (valid when deg<=MAXNB)
__device__ __align__(16) uint32_t g_outkey[NFLAT];
__device__ int      g_outidx[NFLAT];
__device__ int      g_done;                 // fan-in counter (reset by adj_kernel)

// monotone map: float -> uint32 such that u(a) < u(b) <=> a < b
__device__ __forceinline__ uint32_t fkey(float f) {
    uint32_t u = __float_as_uint(f);
    return (u & 0x80000000u) ? ~u : (u | 0x80000000u);
}

// 500 blocks x 256: inline-decode all boxes to LDS, then wave-per-row IoU bits.
// Block 0 persists g_boxes and resets g_done.
__global__ __launch_bounds__(256) void adj_kernel(const float* __restrict__ deltas,
                                                  const float* __restrict__ props) {
    __shared__ float4 bb[N_PROP];           // 32 KB
    const int tid = threadIdx.x;
    const float4* p4 = (const float4*)props;
    const float4* d4 = (const float4*)deltas;
    for (int i = tid; i < N_PROP; i += 256) {
        float4 p = p4[i], d = d4[i];
        float w = p.z - p.x + 1.0f, h = p.w - p.y + 1.0f;
        float cx = p.x + 0.5f*w,  cy = p.y + 0.5f*h;
        float pcx = d.x*w + cx, pcy = d.y*h + cy;
        float pw = expf(d.z)*w, ph = expf(d.w)*h;
        bb[i] = make_float4(pcx - 0.5f*pw, pcy - 0.5f*ph, pcx + 0.5f*pw, pcy + 0.5f*ph);
    }
    __syncthreads();
    if (blockIdx.x == 0) {
        for (int i = tid; i < N_PROP; i += 256) g_boxes[i] = bb[i];
        if (tid == 0) g_done = 0;
    }
    const int row = blockIdx.x * 4 + (tid >> 6);
    const int lane = tid & 63;
    float4 bi = bb[row];
    float ai = fmaxf(bi.z - bi.x, 0.0f) * fmaxf(bi.w - bi.y, 0.0f);
    uint32_t bits = 0u;
    #pragma unroll 8
    for (int b = 0; b < 32; ++b) {
        int j = lane * 32 + b;
        if (j < N_PROP && j != row) {
            float4 bj = bb[j];
            float aj = fmaxf(bj.z - bj.x, 0.0f) * fmaxf(bj.w - bj.y, 0.0f);
            float ix1 = fmaxf(bi.x, bj.x);
            float iy1 = fmaxf(bi.y, bj.y);
            float ix2 = fminf(bi.z, bj.z);
            float iy2 = fminf(bi.w, bj.w);
            float inter = fmaxf(ix2 - ix1, 0.0f) * fmaxf(iy2 - iy1, 0.0f);
            float uni = ai + aj - inter;
            if (inter > 0.7f * uni) bits |= (1u << b);
        }
    }
    g_adj[row * 64 + lane] = bits;
    // deterministic neighbor-list fill: wave prefix scan of popcounts
    int cnt = __popc(bits);
    int incl = cnt;
    for (int off = 1; off < 64; off <<= 1) {
        int v = __shfl_up(incl, off);
        if (lane >= off) incl += v;
    }
    int base = incl - cnt;
    if (lane == 63) g_deg[row] = incl;
    uint32_t t = bits; int k = 0;
    while (t) {
        int b = __ffs(t) - 1; t &= t - 1;
        int s = base + k; ++k;
        if (s < MAXNB) g_nbr[row * MAXNB + s] = lane * 32 + b;
    }
}

// Block-cooperative (256 thr): among {i in [0,n): !state || state[i]==want},
// select top-t by (skey desc, idx asc); writes them SORTED to outbuf[0..t-1]
// as (key<<32)|(0xFFFFFFFF-i). Requires 1 <= t <= min(count(valid), TOUT+27),
// n <= 8192. Wave-shuffle scans, privatized hists, rank-based placement.
__device__ void select_topt(const uint32_t* __restrict__ skey,
                            const unsigned char* state, int want,
                            int n, int t,
                            uint32_t* hist4,    // [4*256]
                            uint32_t* hist,     // [256]
                            uint64_t* cand,     // [CAP]
                            uint64_t* outbuf,   // [>= t]
                            int* sh) {
    const int tid = threadIdx.x;
    const int wv = tid >> 6, lane = tid & 63;
    uint32_t prefix = 0, above = 0, thr = 0, Bi = 0;
    int shift = 24;
    bool tie = false;
    for (;;) {
        for (int b = tid; b < 1024; b += 256) hist4[b] = 0;
        __syncthreads();
        for (int i = tid; i < n; i += 256) {
            if (!state || state[i] == want) {
                uint32_t k = skey[i];
                if (shift == 24 || (k >> (shift + 8)) == prefix)
                    atomicAdd(&hist4[(wv << 8) + ((k >> shift) & 0xFF)], 1u);
            }
        }
        __syncthreads();
        if (tid < 256) hist[tid] = hist4[tid] + hist4[256+tid] + hist4[512+tid] + hist4[768+tid];
        __syncthreads();
        if (tid < 64) {     // wave-0 suffix scan (no barriers inside)
            uint32_t h0 = hist[4*lane], h1 = hist[4*lane+1], h2 = hist[4*lane+2], h3 = hist[4*lane+3];
            uint32_t T = h0 + h1 + h2 + h3;
            uint32_t I = T;
            for (int off = 1; off < 64; off <<= 1) {
                uint32_t v = __shfl_down(I, off);
                if (lane + off < 64) I += v;
            }
            uint32_t S = I - T;     // sum over lanes > lane
            uint32_t o3 = h3 + S, o2 = h2 + o3, o1 = h1 + o2, o0 = h0 + o1;
            hist[4*lane] = o0; hist[4*lane+1] = o1; hist[4*lane+2] = o2; hist[4*lane+3] = o3;
        }
        __syncthreads();
        if (tid < 256) {    // B = max b with above + suffix(b) >= t
            uint32_t ci = above + hist[tid];
            uint32_t cn = (tid < 255) ? above + hist[tid+1] : above;
            if (ci >= (uint32_t)t && (tid == 255 || cn < (uint32_t)t)) sh[1] = tid;
        }
        __syncthreads();
        int B = sh[1];
        uint32_t nCand = above + hist[B];
        uint32_t nAbove = above + ((B < 255) ? hist[B+1] : 0u);
        __syncthreads();
        thr = (prefix << 8) | (uint32_t)B;
        if (nCand <= CAP) break;
        if (shift == 0) {
            // mass exact-key ties at thr: take smallest indices (per-32-word cut)
            uint32_t needS = (uint32_t)t - nAbove;      // >= 1
            for (int b = tid; b < 1024; b += 256) hist4[b] = 0;
            __syncthreads();
            for (int i = tid; i < n; i += 256)
                if ((!state || state[i] == want) && skey[i] == thr)
                    atomicAdd(&hist4[(wv << 8) + (i >> 5)], 1u);
            __syncthreads();
            if (tid < 256) hist[tid] = hist4[tid] + hist4[256+tid] + hist4[512+tid] + hist4[768+tid];
            __syncthreads();
            if (tid < 64) {     // wave-0 ascending inclusive scan
                uint32_t h0 = hist[4*lane], h1 = hist[4*lane+1], h2 = hist[4*lane+2], h3 = hist[4*lane+3];
                uint32_t T = h0 + h1 + h2 + h3;
                uint32_t I = T;
                for (int off = 1; off < 64; off <<= 1) {
                    uint32_t v = __shfl_up(I, off);
                    if (lane >= off) I += v;
                }
                uint32_t S = I - T;     // sum over lanes < lane
                uint32_t a0 = S + h0, a1 = a0 + h1, a2 = a1 + h2, a3 = a2 + h3;
                hist[4*lane] = a0; hist[4*lane+1] = a1; hist[4*lane+2] = a2; hist[4*lane+3] = a3;
            }
            __syncthreads();
            if (tid < 256) {
                if (hist[tid] >= needS && (tid == 0 || hist[tid-1] < needS)) sh[1] = tid;
            }
            __syncthreads();
            Bi = (uint32_t)sh[1];
            tie = true;
            __syncthreads();
            break;
        }
        prefix = thr; above = nAbove; shift -= 8;
    }
    // ballot-aggregated compaction into cand[0..m-1] (m <= CAP by construction)
    if (tid == 0) sh[2] = 0;
    __syncthreads();
    for (int i0 = 0; i0 < n; i0 += 256) {
        int i = i0 + tid;
        bool take = false; uint32_t k = 0;
        if (i < n && (!state || state[i] == want)) {
            k = skey[i];
            take = tie ? (k > thr || (k == thr && (uint32_t)(i >> 5) <= Bi))
                       : ((k >> shift) >= thr);
        }
        unsigned long long m = __ballot(take);
        if (m) {
            int leader = __ffsll((long long)m) - 1;
            int wbase = 0;
            if (lane == leader) wbase = atomicAdd(&sh[2], (int)__popcll(m));
            wbase = __shfl(wbase, leader);
            if (take) {
                int pos = wbase + __popcll(m & ((1ull << lane) - 1ull));
                cand[pos] = ((uint64_t)k << 32) | (uint32_t)(0xFFFFFFFFu - (uint32_t)i);
            }
        }
    }
    __syncthreads();
    int m = sh[2];
    // rank-based placement: keys u64-unique; top-t land sorted in outbuf
    for (int s = tid; s < m; s += 256) {
        uint64_t e = cand[s];
        int r = 0;
        for (int s2 = 0; s2 < m; ++s2) r += (cand[s2] > e) ? 1 : 0;
        if (r < t) outbuf[r] = e;
    }
    __syncthreads();
}

// shared-memory layout for nms_class (45.8 KB)
#define SM_SKEY   0        // 8000 B (nms) / 32000 B (tail gkey)
#define SM_STATE  8000     // 2000 B
#define SM_SDEG   10048    // 4000 B
#define SM_HIST4  32000    // 4096 B
#define SM_HIST   36096    // 1024 B
#define SM_CAND   37120    // 6144 B
#define SM_OUT    43264    // 2432 B
#define SM_SH     45696    // 64 B
#define SM_BYTES  45760

// one block per class: sparse fixpoint NMS (== greedy), radix-select top-100;
// last-finishing block runs the global top-300 + gather as a tail.
__global__ __launch_bounds__(256) void nms_class_kernel(const float* __restrict__ scores,
                                                        float* __restrict__ out) {
    __shared__ __align__(16) char smem[SM_BYTES];
    uint32_t* skey  = (uint32_t*)(smem + SM_SKEY);
    unsigned char* state = (unsigned char*)(smem + SM_STATE);
    uint16_t* sdeg  = (uint16_t*)(smem + SM_SDEG);
    uint32_t* hist4 = (uint32_t*)(smem + SM_HIST4);
    uint32_t* hist  = (uint32_t*)(smem + SM_HIST);
    uint64_t* cand  = (uint64_t*)(smem + SM_CAND);
    uint64_t* outbuf= (uint64_t*)(smem + SM_OUT);
    int* sh         = (int*)(smem + SM_SH);
    __shared__ int s_changed, s_kept;
    const int c = blockIdx.x, tid = threadIdx.x;

    for (int i = tid; i < N_PROP; i += 256) {
        skey[i] = fkey(scores[i * NCLS + c]);
        int d = g_deg[i];
        sdeg[i] = (uint16_t)d;
        state[i] = (d == 0) ? ST_KEPT : ST_UNDEC;
    }
    if (tid == 0) s_changed = 0;
    __syncthreads();

    // fixpoint: keep[i] <=> no adjacent better j with keep[j]  (== greedy NMS)
    for (;;) {
        for (int i = tid; i < N_PROP; i += 256) {
            if (state[i] != ST_UNDEC) continue;
            uint32_t ki = skey[i];
            int deg = sdeg[i];
            bool anyKept = false, anyUndec = false;
            if (deg <= MAXNB) {
                for (int nn = 0; nn < deg; ++nn) {
                    int j = g_nbr[i * MAXNB + nn];
                    uint32_t kj = skey[j];
                    if (kj > ki || (kj == ki && j < i)) {
                        unsigned char stj = state[j];
                        if (stj == ST_KEPT) anyKept = true;
                        else if (stj == ST_UNDEC) anyUndec = true;
                    }
                }
            } else {
                for (int w = 0; w < 64; ++w) {
                    uint32_t bits = g_adj[i * 64 + w];
                    while (bits) {
                        int b = __ffs(bits) - 1; bits &= bits - 1;
                        int j = w * 32 + b;
                        uint32_t kj = skey[j];
                        if (kj > ki || (kj == ki && j < i)) {
                            unsigned char stj = state[j];
                            if (stj == ST_KEPT) anyKept = true;
                            else if (stj == ST_UNDEC) anyUndec = true;
                        }
                    }
                }
            }
            if (anyKept)        { state[i] = ST_SUPP; s_changed = 1; }
            else if (!anyUndec) { state[i] = ST_KEPT; s_changed = 1; }
        }
        __syncthreads();
        int ch = s_changed;
        __syncthreads();
        if (!ch) break;
        if (tid == 0) s_changed = 0;
        __syncthreads();
    }

    if (tid == 0) s_kept = 0;
    __syncthreads();
    {
        int local = 0;
        for (int i = tid; i < N_PROP; i += 256) local += (state[i] == ST_KEPT) ? 1 : 0;
        if (local) atomicAdd(&s_kept, local);
    }
    __syncthreads();
    const int kept = s_kept;

    const int t1 = kept < MAXPC ? kept : MAXPC;     // kept >= 1 always
    select_topt(skey, state, ST_KEPT, N_PROP, t1, hist4, hist, cand, outbuf, sh);
    for (int r = tid; r < t1; r += 256) {
        uint64_t e = outbuf[r];
        g_outkey[c * MAXPC + r] = (uint32_t)(e >> 32);
        g_outidx[c * MAXPC + r] = (int)(0xFFFFFFFFu - (uint32_t)e);
    }
    if (kept < MAXPC) {
        __syncthreads();
        const int t2 = MAXPC - kept;                // suppressed count >= t2
        select_topt(skey, state, ST_SUPP, N_PROP, t2, hist4, hist, cand, outbuf, sh);
        for (int r = tid; r < t2; r += 256) {
            uint64_t e = outbuf[r];
            g_outkey[c * MAXPC + kept + r] = FKEY_NEGINF;
            g_outidx[c * MAXPC + kept + r] = (int)(0xFFFFFFFFu - (uint32_t)e);
        }
    }
    __syncthreads();

    // ---- fan-in: last block to finish runs global top-300 + gather ----
    __threadfence();                                // release our outkey/outidx
    if (tid == 0) sh[3] = atomicAdd(&g_done, 1);
    __syncthreads();
    if (sh[3] != NCLS - 1) return;
    __threadfence();                                // acquire others' writes

    uint32_t* gkey = (uint32_t*)(smem + SM_SKEY);   // reuse: 32000 B
    const uint4* gk4 = (const uint4*)g_outkey;
    uint4* lk4 = (uint4*)gkey;
    for (int q = tid; q < NFLAT/4; q += 256) lk4[q] = gk4[q];
    __syncthreads();
    select_topt(gkey, nullptr, 0, NFLAT, MAXIMG, hist4, hist, cand, outbuf, sh);
    for (int r = tid; r < MAXIMG; r += 256) {
        uint64_t e = outbuf[r];
        int f = (int)(0xFFFFFFFFu - (uint32_t)e);
        int pi = g_outidx[f];
        float4 b = g_boxes[pi];
        out[r*4+0] = b.x;
        out[r*4+1] = b.y;
        out[r*4+2] = b.z;
        out[r*4+3] = b.w;
        out[MAXIMG*4 + r] = (float)(f / MAXPC);
    }
}

extern "C" void kernel_launch(void* const* d_in, const int* in_sizes, int n_in,
                              void* d_out, int out_size, void* d_ws, size_t ws_size,
                              hipStream_t stream) {
    const float* deltas = (const float*)d_in[0];   // roi_bboxes_txtytwth [2000,4]
    const float* scores = (const float*)d_in[1];   // roi_score [2000,80]
    const float* props  = (const float*)d_in[2];   // rpn_proposals_bboxes [2000,4]
    float* out = (float*)d_out;                    // 1200 box floats + 300 class floats

    adj_kernel<<<N_PROP/4, 256, 0, stream>>>(deltas, props);
    nms_class_kernel<<<NCLS, 256, 0, stream>>>(scores, out);
}

// Round 5
// 91.973 us; speedup vs baseline: 1.0362x; 1.0362x over previous
//
#include <hip/hip_runtime.h>
#include <stdint.h>

#define N_PROP 2000
#define NCLS 80
#define MAXPC 100
#define MAXIMG 300
#define NFLAT (NCLS*MAXPC)   // 8000
#define MAXNB 32
#define CAP 768
#define FKEY_NEGINF 0x007FFFFFu

#define ST_UNDEC 0
#define ST_KEPT 1
#define ST_SUPP 2

// persistent device scratch (fully rewritten every launch -> deterministic)
__device__ float4   g_boxes[N_PROP];
__device__ uint32_t g_adj[N_PROP * 64];     // bitset rows (self-bit excluded)
__device__ int      g_deg[N_PROP];
__device__ int      g_nbr[N_PROP * MAXNB];  // neighbor lists (valid when deg<=MAXNB)
__device__ __align__(16) uint32_t g_outkey[NFLAT];
__device__ int      g_outidx[NFLAT];
__device__ int      g_done;                 // fan-in counter (reset by adj_kernel)

// monotone map: float -> uint32 such that u(a) < u(b) <=> a < b
__device__ __forceinline__ uint32_t fkey(float f) {
    uint32_t u = __float_as_uint(f);
    return (u & 0x80000000u) ? ~u : (u | 0x80000000u);
}

// 500 blocks x 256: inline-decode all boxes to LDS, then wave-per-row IoU bits.
// Block 0 persists g_boxes and resets g_done.
__global__ __launch_bounds__(256) void adj_kernel(const float* __restrict__ deltas,
                                                  const float* __restrict__ props) {
    __shared__ float4 bb[N_PROP];           // 32 KB
    const int tid = threadIdx.x;
    const float4* p4 = (const float4*)props;
    const float4* d4 = (const float4*)deltas;
    for (int i = tid; i < N_PROP; i += 256) {
        float4 p = p4[i], d = d4[i];
        float w = p.z - p.x + 1.0f, h = p.w - p.y + 1.0f;
        float cx = p.x + 0.5f*w,  cy = p.y + 0.5f*h;
        float pcx = d.x*w + cx, pcy = d.y*h + cy;
        float pw = expf(d.z)*w, ph = expf(d.w)*h;
        bb[i] = make_float4(pcx - 0.5f*pw, pcy - 0.5f*ph, pcx + 0.5f*pw, pcy + 0.5f*ph);
    }
    __syncthreads();
    if (blockIdx.x == 0) {
        for (int i = tid; i < N_PROP; i += 256) g_boxes[i] = bb[i];
        if (tid == 0) g_done = 0;
    }
    const int row = blockIdx.x * 4 + (tid >> 6);
    const int lane = tid & 63;
    float4 bi = bb[row];
    float ai = fmaxf(bi.z - bi.x, 0.0f) * fmaxf(bi.w - bi.y, 0.0f);
    uint32_t bits = 0u;
    #pragma unroll 8
    for (int b = 0; b < 32; ++b) {
        int j = lane * 32 + b;
        if (j < N_PROP && j != row) {
            float4 bj = bb[j];
            float aj = fmaxf(bj.z - bj.x, 0.0f) * fmaxf(bj.w - bj.y, 0.0f);
            float ix1 = fmaxf(bi.x, bj.x);
            float iy1 = fmaxf(bi.y, bj.y);
            float ix2 = fminf(bi.z, bj.z);
            float iy2 = fminf(bi.w, bj.w);
            float inter = fmaxf(ix2 - ix1, 0.0f) * fmaxf(iy2 - iy1, 0.0f);
            float uni = ai + aj - inter;
            if (inter > 0.7f * uni) bits |= (1u << b);
        }
    }
    g_adj[row * 64 + lane] = bits;
    // deterministic neighbor-list fill: wave prefix scan of popcounts
    int cnt = __popc(bits);
    int incl = cnt;
    for (int off = 1; off < 64; off <<= 1) {
        int v = __shfl_up(incl, off);
        if (lane >= off) incl += v;
    }
    int base = incl - cnt;
    if (lane == 63) g_deg[row] = incl;
    uint32_t t = bits; int k = 0;
    while (t) {
        int b = __ffs(t) - 1; t &= t - 1;
        int s = base + k; ++k;
        if (s < MAXNB) g_nbr[row * MAXNB + s] = lane * 32 + b;
    }
}

// Block-cooperative (256 thr): among {i in [0,n): !state || state[i]==want},
// select top-t by (skey desc, idx asc); writes them SORTED to outbuf[0..t-1]
// as (key<<32)|(0xFFFFFFFF-i). Requires 1 <= t <= min(count(valid), 300),
// n <= 8192. 11-bit radix levels, hybrid (ballot/atomic) histogram,
// bin-ordered compaction + local ranking on the fast path.
__device__ void select_topt(const uint32_t* __restrict__ skey,
                            const unsigned char* state, int want,
                            int n, int t,
                            uint32_t* hist,     // [>=2049]
                            uint32_t* binFill,  // [2048] (also scan scratch)
                            uint64_t* cand,     // [CAP]
                            uint64_t* outbuf,   // [>= t]
                            int* sh) {
    const int tid = threadIdx.x;
    const int lane = tid & 63;
    uint32_t prefix = 0, above = 0, thr = 0, Bi = 0, mask = 0x7FFu;
    int shift = 21, width = 11;
    bool tie = false;
    for (;;) {
        for (int b = tid; b <= 2048; b += 256) hist[b] = 0;
        __syncthreads();
        // histogram of (k >> shift) & mask among prefix-matching valid keys
        for (int i0 = 0; i0 < n; i0 += 256) {
            int i = i0 + tid;
            bool valid = false; uint32_t b = 0;
            if (i < n && (!state || state[i] == want)) {
                uint32_t k = skey[i];
                if (shift == 21 || (k >> (shift + width)) == prefix) {
                    valid = true; b = (k >> shift) & mask;
                }
            }
            uint32_t b0 = __shfl(b, 0);
            bool same = valid && (b == b0);
            unsigned long long eq = __ballot(same);
            if (eq == ~0ull) {
                if (lane == 0) atomicAdd(&hist[b0], 64u);
            } else if (valid) {
                atomicAdd(&hist[b], 1u);
            }
        }
        __syncthreads();
        // suffix scan: hist[b] <- count(valid, bin >= b); hist[2048] stays 0
        {
            uint32_t c8 = 0;
            #pragma unroll 8
            for (int q = 0; q < 8; ++q) c8 += hist[tid*8 + q];
            binFill[tid] = c8;
            __syncthreads();
            if (tid < 64) {
                uint32_t h0=binFill[4*lane], h1=binFill[4*lane+1], h2=binFill[4*lane+2], h3=binFill[4*lane+3];
                uint32_t T = h0+h1+h2+h3, I = T;
                for (int off = 1; off < 64; off <<= 1) {
                    uint32_t v = __shfl_down(I, off);
                    if (lane + off < 64) I += v;
                }
                uint32_t S = I - T;
                uint32_t o3=h3+S, o2=h2+o3, o1=h1+o2, o0=h0+o1;
                binFill[4*lane]=o0; binFill[4*lane+1]=o1; binFill[4*lane+2]=o2; binFill[4*lane+3]=o3;
            }
            __syncthreads();
            uint32_t run = (tid == 255) ? 0u : binFill[tid+1];
            uint32_t t7,t6,t5,t4,t3,t2,t1,t0;
            run += hist[tid*8+7]; t7 = run;
            run += hist[tid*8+6]; t6 = run;
            run += hist[tid*8+5]; t5 = run;
            run += hist[tid*8+4]; t4 = run;
            run += hist[tid*8+3]; t3 = run;
            run += hist[tid*8+2]; t2 = run;
            run += hist[tid*8+1]; t1 = run;
            run += hist[tid*8+0]; t0 = run;
            hist[tid*8+0]=t0; hist[tid*8+1]=t1; hist[tid*8+2]=t2; hist[tid*8+3]=t3;
            hist[tid*8+4]=t4; hist[tid*8+5]=t5; hist[tid*8+6]=t6; hist[tid*8+7]=t7;
            __syncthreads();
        }
        // B = max b with above + suffix(b) >= t  (unique crossing)
        #pragma unroll 8
        for (int q = 0; q < 8; ++q) {
            int b = tid*8 + q;
            uint32_t sb = hist[b], sb1 = hist[b+1];
            if (above + sb >= (uint32_t)t && above + sb1 < (uint32_t)t) sh[1] = b;
        }
        __syncthreads();
        int B = sh[1];
        uint32_t nCand = above + hist[B];
        uint32_t nAbove = above + hist[B+1];
        thr = (prefix << width) | (uint32_t)B;
        if (nCand <= CAP) { __syncthreads(); break; }
        if (shift == 0) {
            // mass exact-key ties at thr: take smallest indices (32-idx word cut)
            uint32_t needS = (uint32_t)t - nAbove;      // >= 1
            __syncthreads();
            for (int b = tid; b < 257; b += 256) hist[b] = 0;
            __syncthreads();
            for (int i = tid; i < n; i += 256)
                if ((!state || state[i] == want) && skey[i] == thr)
                    atomicAdd(&hist[i >> 5], 1u);
            __syncthreads();
            if (tid < 64) {     // ascending inclusive scan of hist[0..255]
                uint32_t h0=hist[4*lane], h1=hist[4*lane+1], h2=hist[4*lane+2], h3=hist[4*lane+3];
                uint32_t T = h0+h1+h2+h3, I = T;
                for (int off = 1; off < 64; off <<= 1) {
                    uint32_t v = __shfl_up(I, off);
                    if (lane >= off) I += v;
                }
                uint32_t S = I - T;
                uint32_t a0=S+h0, a1=a0+h1, a2=a1+h2, a3=a2+h3;
                hist[4*lane]=a0; hist[4*lane+1]=a1; hist[4*lane+2]=a2; hist[4*lane+3]=a3;
            }
            __syncthreads();
            if (hist[tid] >= needS && (tid == 0 || hist[tid-1] < needS)) sh[1] = tid;
            __syncthreads();
            Bi = (uint32_t)sh[1];
            tie = true;
            __syncthreads();
            break;
        }
        prefix = thr; above = nAbove;
        if (shift == 21) { shift = 10; width = 11; mask = 0x7FFu; }
        else             { shift = 0;  width = 10; mask = 0x3FFu; }
        __syncthreads();        // hist reads done before next-level zeroing
    }

    if (!tie && above == 0) {
        // -------- fast path: bin-ordered compaction + same-bin ranking --------
        for (int b = tid; b < 2048; b += 256) binFill[b] = 0;
        if (tid == 0) sh[2] = 0;    // unused here, kept consistent
        __syncthreads();
        for (int i = tid; i < n; i += 256) {
            if (!state || state[i] == want) {
                uint32_t k = skey[i];
                if ((k >> shift) >= thr) {
                    uint32_t be = (k >> shift) & mask;
                    uint32_t pos = hist[be+1] + atomicAdd(&binFill[be], 1u);
                    cand[pos] = ((uint64_t)k << 32) | (uint32_t)(0xFFFFFFFFu - (uint32_t)i);
                }
            }
        }
        __syncthreads();
        int m = (int)0 + (int)0; // silence unused warnings pattern
        m = (int)(hist[(uint32_t)thr & mask] + 0u); // candidates = suffix(B); B = thr&mask when above==0
        // rank within own bin only; cross-bin order comes from bin bases
        for (int s = tid; s < (int)m; s += 256) {
            uint64_t e = cand[s];
            uint32_t k = (uint32_t)(e >> 32);
            uint32_t be = (k >> shift) & mask;
            uint32_t base = hist[be+1];
            uint32_t cnt = hist[be] - base;
            uint32_t r = base;
            for (uint32_t s2 = base; s2 < base + cnt; ++s2)
                r += (cand[s2] > e) ? 1u : 0u;
            if (r < (uint32_t)t) outbuf[r] = e;
        }
        __syncthreads();
    } else {
        // -------- general path: unordered compaction + full ranking --------
        if (tid == 0) sh[2] = 0;
        __syncthreads();
        for (int i0 = 0; i0 < n; i0 += 256) {
            int i = i0 + tid;
            bool take = false; uint32_t k = 0;
            if (i < n && (!state || state[i] == want)) {
                k = skey[i];
                take = tie ? (k > thr || (k == thr && (uint32_t)(i >> 5) <= Bi))
                           : ((k >> shift) >= thr);
            }
            unsigned long long mm = __ballot(take);
            if (mm) {
                int leader = __ffsll((long long)mm) - 1;
                int wbase = 0;
                if (lane == leader) wbase = atomicAdd(&sh[2], (int)__popcll(mm));
                wbase = __shfl(wbase, leader);
                if (take) {
                    int pos = wbase + __popcll(mm & ((1ull << lane) - 1ull));
                    cand[pos] = ((uint64_t)k << 32) | (uint32_t)(0xFFFFFFFFu - (uint32_t)i);
                }
            }
        }
        __syncthreads();
        int m = sh[2];
        for (int s = tid; s < m; s += 256) {
            uint64_t e = cand[s];
            uint32_t r = 0;
            for (int s2 = 0; s2 < m; ++s2) r += (cand[s2] > e) ? 1u : 0u;
            if (r < (uint32_t)t) outbuf[r] = e;
        }
        __syncthreads();
    }
}

// shared-memory layout (~55.7 KB)
#define SM_A      0        // class: skey 8000 | state @8000 | sdeg @10048; tail: gkey 32000
#define SM_HIST   32000    // 2052*4 = 8208 (uses [0..2048])
#define SM_BINF   40208    // 2048*4 = 8192
#define SM_CAND   48400    // 768*8 = 6144
#define SM_OUT    54544    // 304*8 = 2432
#define SM_SH     56976    // 32
#define SM_BYTES  57008

// one block per class: sparse fixpoint NMS (== greedy), radix-select top-100;
// last-finishing block runs the global top-300 + gather as a tail.
__global__ __launch_bounds__(256) void nms_class_kernel(const float* __restrict__ scores,
                                                        float* __restrict__ out) {
    __shared__ __align__(16) char smem[SM_BYTES];
    uint32_t* skey  = (uint32_t*)(smem + SM_A);
    unsigned char* state = (unsigned char*)(smem + SM_A + 8000);
    uint16_t* sdeg  = (uint16_t*)(smem + SM_A + 10048);
    uint32_t* hist  = (uint32_t*)(smem + SM_HIST);
    uint32_t* binF  = (uint32_t*)(smem + SM_BINF);
    uint64_t* cand  = (uint64_t*)(smem + SM_CAND);
    uint64_t* outbuf= (uint64_t*)(smem + SM_OUT);
    int* sh         = (int*)(smem + SM_SH);
    __shared__ int s_changed, s_kept;
    const int c = blockIdx.x, tid = threadIdx.x;

    for (int i = tid; i < N_PROP; i += 256) {
        skey[i] = fkey(scores[i * NCLS + c]);
        int d = g_deg[i];
        sdeg[i] = (uint16_t)d;
        state[i] = (d == 0) ? ST_KEPT : ST_UNDEC;
    }
    if (tid == 0) s_changed = 0;
    __syncthreads();

    // fixpoint: keep[i] <=> no adjacent better j with keep[j]  (== greedy NMS)
    for (;;) {
        for (int i = tid; i < N_PROP; i += 256) {
            if (state[i] != ST_UNDEC) continue;
            uint32_t ki = skey[i];
            int deg = sdeg[i];
            bool anyKept = false, anyUndec = false;
            if (deg <= MAXNB) {
                for (int nn = 0; nn < deg; ++nn) {
                    int j = g_nbr[i * MAXNB + nn];
                    uint32_t kj = skey[j];
                    if (kj > ki || (kj == ki && j < i)) {
                        unsigned char stj = state[j];
                        if (stj == ST_KEPT) anyKept = true;
                        else if (stj == ST_UNDEC) anyUndec = true;
                    }
                }
            } else {
                for (int w = 0; w < 64; ++w) {
                    uint32_t bits = g_adj[i * 64 + w];
                    while (bits) {
                        int b = __ffs(bits) - 1; bits &= bits - 1;
                        int j = w * 32 + b;
                        uint32_t kj = skey[j];
                        if (kj > ki || (kj == ki && j < i)) {
                            unsigned char stj = state[j];
                            if (stj == ST_KEPT) anyKept = true;
                            else if (stj == ST_UNDEC) anyUndec = true;
                        }
                    }
                }
            }
            if (anyKept)        { state[i] = ST_SUPP; s_changed = 1; }
            else if (!anyUndec) { state[i] = ST_KEPT; s_changed = 1; }
        }
        __syncthreads();
        int ch = s_changed;
        __syncthreads();
        if (!ch) break;
        if (tid == 0) s_changed = 0;
        __syncthreads();
    }

    if (tid == 0) s_kept = 0;
    __syncthreads();
    {
        int local = 0;
        for (int i = tid; i < N_PROP; i += 256) local += (state[i] == ST_KEPT) ? 1 : 0;
        if (local) atomicAdd(&s_kept, local);
    }
    __syncthreads();
    const int kept = s_kept;

    const int t1 = kept < MAXPC ? kept : MAXPC;     // kept >= 1 always
    select_topt(skey, state, ST_KEPT, N_PROP, t1, hist, binF, cand, outbuf, sh);
    for (int r = tid; r < t1; r += 256) {
        uint64_t e = outbuf[r];
        g_outkey[c * MAXPC + r] = (uint32_t)(e >> 32);
        g_outidx[c * MAXPC + r] = (int)(0xFFFFFFFFu - (uint32_t)e);
    }
    if (kept < MAXPC) {
        __syncthreads();
        const int t2 = MAXPC - kept;                // suppressed count >= t2
        select_topt(skey, state, ST_SUPP, N_PROP, t2, hist, binF, cand, outbuf, sh);
        for (int r = tid; r < t2; r += 256) {
            uint64_t e = outbuf[r];
            g_outkey[c * MAXPC + kept + r] = FKEY_NEGINF;
            g_outidx[c * MAXPC + kept + r] = (int)(0xFFFFFFFFu - (uint32_t)e);
        }
    }
    __syncthreads();

    // ---- fan-in: last block to finish runs global top-300 + gather ----
    __threadfence();                                // release our outkey/outidx
    if (tid == 0) sh[3] = atomicAdd(&g_done, 1);
    __syncthreads();
    if (sh[3] != NCLS - 1) return;
    __threadfence();                                // acquire others' writes

    uint32_t* gkey = (uint32_t*)(smem + SM_A);      // reuse: 32000 B
    const uint4* gk4 = (const uint4*)g_outkey;
    uint4* lk4 = (uint4*)gkey;
    for (int q = tid; q < NFLAT/4; q += 256) lk4[q] = gk4[q];
    __syncthreads();
    select_topt(gkey, nullptr, 0, NFLAT, MAXIMG, hist, binF, cand, outbuf, sh);
    for (int r = tid; r < MAXIMG; r += 256) {
        uint64_t e = outbuf[r];
        int f = (int)(0xFFFFFFFFu - (uint32_t)e);
        int pi = g_outidx[f];
        float4 b = g_boxes[pi];
        out[r*4+0] = b.x;
        out[r*4+1] = b.y;
        out[r*4+2] = b.z;
        out[r*4+3] = b.w;
        out[MAXIMG*4 + r] = (float)(f / MAXPC);
    }
}

extern "C" void kernel_launch(void* const* d_in, const int* in_sizes, int n_in,
                              void* d_out, int out_size, void* d_ws, size_t ws_size,
                              hipStream_t stream) {
    const float* deltas = (const float*)d_in[0];   // roi_bboxes_txtytwth [2000,4]
    const float* scores = (const float*)d_in[1];   // roi_score [2000,80]
    const float* props  = (const float*)d_in[2];   // rpn_proposals_bboxes [2000,4]
    float* out = (float*)d_out;                    // 1200 box floats + 300 class floats

    adj_kernel<<<N_PROP/4, 256, 0, stream>>>(deltas, props);
    nms_class_kernel<<<NCLS, 256, 0, stream>>>(scores, out);
}

// Round 6
// 86.861 us; speedup vs baseline: 1.0972x; 1.0589x over previous
//
#include <hip/hip_runtime.h>
#include <stdint.h>

#define N_PROP 2000
#define NCLS 80
#define MAXPC 100
#define MAXIMG 300
#define NFLAT (NCLS*MAXPC)   // 8000
#define MAXNB 32
#define CAP 768
#define FKEY_NEGINF 0x007FFFFFu

#define ST_UNDEC 0
#define ST_KEPT 1
#define ST_SUPP 2

// persistent device scratch (fully rewritten every launch -> deterministic)
__device__ float4   g_boxes[N_PROP];
__device__ uint32_t g_adj[N_PROP * 64];     // bitset rows (self-bit excluded)
__device__ int      g_deg[N_PROP];
__device__ int      g_nbr[N_PROP * MAXNB];  // neighbor lists (valid when deg<=MAXNB)
__device__ __align__(16) uint32_t g_outkey[NFLAT];
__device__ int      g_outidx[NFLAT];
__device__ __align__(16) float g_scoresT[NCLS * N_PROP];  // transposed scores
__device__ uint32_t g_ghist[2048];          // global clamped-bin histogram
__device__ int      g_done;                 // fan-in counter

// monotone map: float -> uint32 such that u(a) < u(b) <=> a < b
__device__ __forceinline__ uint32_t fkey(float f) {
    uint32_t u = __float_as_uint(f);
    return (u & 0x80000000u) ? ~u : (u | 0x80000000u);
}

// fixed monotone clamped binning for the global-top-300 histogram:
// 2048 bins of width 2^12 over [fkey(0.5), fkey(1.0)) = [0xBF000000, 0xBF800000)
__device__ __forceinline__ uint32_t cbin(uint32_t k) {
    if (k < 0xBF000000u) return 0u;
    uint32_t b = (k - 0xBF000000u) >> 12;
    return b > 2047u ? 2047u : b;
}

// 500 blocks x 256: inline-decode all boxes to LDS, wave-per-row IoU bits,
// score transpose, ghist zero. Block 0 persists g_boxes and resets g_done.
__global__ __launch_bounds__(256) void adj_kernel(const float* __restrict__ deltas,
                                                  const float* __restrict__ props,
                                                  const float* __restrict__ scores) {
    __shared__ float4 bb[N_PROP];           // 32 KB
    const int tid = threadIdx.x;
    const float4* p4 = (const float4*)props;
    const float4* d4 = (const float4*)deltas;
    for (int i = tid; i < N_PROP; i += 256) {
        float4 p = p4[i], d = d4[i];
        float w = p.z - p.x + 1.0f, h = p.w - p.y + 1.0f;
        float cx = p.x + 0.5f*w,  cy = p.y + 0.5f*h;
        float pcx = d.x*w + cx, pcy = d.y*h + cy;
        float pw = expf(d.z)*w, ph = expf(d.w)*h;
        bb[i] = make_float4(pcx - 0.5f*pw, pcy - 0.5f*ph, pcx + 0.5f*pw, pcy + 0.5f*ph);
    }
    // coalesced-read score transpose: flat = i*80+c -> g_scoresT[c*2000+i]
    {
        int base = blockIdx.x * 320;
        for (int q = tid; q < 320; q += 256) {
            int flat = base + q;
            float v = scores[flat];
            g_scoresT[(flat % NCLS) * N_PROP + (flat / NCLS)] = v;
        }
    }
    if (blockIdx.x < 8) {
        int z = blockIdx.x * 256 + tid;
        if (z < 2048) g_ghist[z] = 0u;
    }
    __syncthreads();
    if (blockIdx.x == 0) {
        for (int i = tid; i < N_PROP; i += 256) g_boxes[i] = bb[i];
        if (tid == 0) g_done = 0;
    }
    const int row = blockIdx.x * 4 + (tid >> 6);
    const int lane = tid & 63;
    float4 bi = bb[row];
    float ai = fmaxf(bi.z - bi.x, 0.0f) * fmaxf(bi.w - bi.y, 0.0f);
    uint32_t bits = 0u;
    #pragma unroll 8
    for (int b = 0; b < 32; ++b) {
        int j = lane * 32 + b;
        if (j < N_PROP && j != row) {
            float4 bj = bb[j];
            float aj = fmaxf(bj.z - bj.x, 0.0f) * fmaxf(bj.w - bj.y, 0.0f);
            float ix1 = fmaxf(bi.x, bj.x);
            float iy1 = fmaxf(bi.y, bj.y);
            float ix2 = fminf(bi.z, bj.z);
            float iy2 = fminf(bi.w, bj.w);
            float inter = fmaxf(ix2 - ix1, 0.0f) * fmaxf(iy2 - iy1, 0.0f);
            float uni = ai + aj - inter;
            if (inter > 0.7f * uni) bits |= (1u << b);
        }
    }
    g_adj[row * 64 + lane] = bits;
    // deterministic neighbor-list fill: wave prefix scan of popcounts
    int cnt = __popc(bits);
    int incl = cnt;
    for (int off = 1; off < 64; off <<= 1) {
        int v = __shfl_up(incl, off);
        if (lane >= off) incl += v;
    }
    int base = incl - cnt;
    if (lane == 63) g_deg[row] = incl;
    uint32_t t = bits; int k = 0;
    while (t) {
        int b = __ffs(t) - 1; t &= t - 1;
        int s = base + k; ++k;
        if (s < MAXNB) g_nbr[row * MAXNB + s] = lane * 32 + b;
    }
}

// Block-cooperative (256 thr): among {i in [0,n): !state || state[i]==want},
// select top-t by (skey desc, idx asc); writes them SORTED to outbuf[0..t-1]
// as (key<<32)|(0xFFFFFFFF-i). Requires 1 <= t <= min(count(valid), 300),
// n <= 8192. 11-bit radix levels, hybrid histogram, bin-ordered fast path.
__device__ void select_topt(const uint32_t* __restrict__ skey,
                            const unsigned char* state, int want,
                            int n, int t,
                            uint32_t* hist,     // [>=2049]
                            uint32_t* binFill,  // [2048]
                            uint64_t* cand,     // [CAP]
                            uint64_t* outbuf,   // [>= t]
                            int* sh) {
    const int tid = threadIdx.x;
    const int lane = tid & 63;
    uint32_t prefix = 0, above = 0, thr = 0, Bi = 0, mask = 0x7FFu;
    int shift = 21, width = 11;
    bool tie = false;
    for (;;) {
        for (int b = tid; b <= 2048; b += 256) hist[b] = 0;
        __syncthreads();
        for (int i0 = 0; i0 < n; i0 += 256) {
            int i = i0 + tid;
            bool valid = false; uint32_t b = 0;
            if (i < n && (!state || state[i] == want)) {
                uint32_t k = skey[i];
                if (shift == 21 || (k >> (shift + width)) == prefix) {
                    valid = true; b = (k >> shift) & mask;
                }
            }
            uint32_t b0 = __shfl(b, 0);
            bool same = valid && (b == b0);
            unsigned long long eq = __ballot(same);
            if (eq == ~0ull) {
                if (lane == 0) atomicAdd(&hist[b0], 64u);
            } else if (valid) {
                atomicAdd(&hist[b], 1u);
            }
        }
        __syncthreads();
        // suffix scan: hist[b] <- count(valid, bin >= b); hist[2048] stays 0
        {
            uint32_t c8 = 0;
            #pragma unroll 8
            for (int q = 0; q < 8; ++q) c8 += hist[tid*8 + q];
            binFill[tid] = c8;
            __syncthreads();
            if (tid < 64) {
                uint32_t h0=binFill[4*lane], h1=binFill[4*lane+1], h2=binFill[4*lane+2], h3=binFill[4*lane+3];
                uint32_t T = h0+h1+h2+h3, I = T;
                for (int off = 1; off < 64; off <<= 1) {
                    uint32_t v = __shfl_down(I, off);
                    if (lane + off < 64) I += v;
                }
                uint32_t S = I - T;
                uint32_t o3=h3+S, o2=h2+o3, o1=h1+o2, o0=h0+o1;
                binFill[4*lane]=o0; binFill[4*lane+1]=o1; binFill[4*lane+2]=o2; binFill[4*lane+3]=o3;
            }
            __syncthreads();
            uint32_t run = (tid == 255) ? 0u : binFill[tid+1];
            uint32_t t7,t6,t5,t4,t3,t2,t1,t0;
            run += hist[tid*8+7]; t7 = run;
            run += hist[tid*8+6]; t6 = run;
            run += hist[tid*8+5]; t5 = run;
            run += hist[tid*8+4]; t4 = run;
            run += hist[tid*8+3]; t3 = run;
            run += hist[tid*8+2]; t2 = run;
            run += hist[tid*8+1]; t1 = run;
            run += hist[tid*8+0]; t0 = run;
            hist[tid*8+0]=t0; hist[tid*8+1]=t1; hist[tid*8+2]=t2; hist[tid*8+3]=t3;
            hist[tid*8+4]=t4; hist[tid*8+5]=t5; hist[tid*8+6]=t6; hist[tid*8+7]=t7;
            __syncthreads();
        }
        #pragma unroll 8
        for (int q = 0; q < 8; ++q) {
            int b = tid*8 + q;
            uint32_t sb = hist[b], sb1 = hist[b+1];
            if (above + sb >= (uint32_t)t && above + sb1 < (uint32_t)t) sh[1] = b;
        }
        __syncthreads();
        int B = sh[1];
        uint32_t nCand = above + hist[B];
        uint32_t nAbove = above + hist[B+1];
        thr = (prefix << width) | (uint32_t)B;
        if (nCand <= CAP) { __syncthreads(); break; }
        if (shift == 0) {
            uint32_t needS = (uint32_t)t - nAbove;      // >= 1
            __syncthreads();
            for (int b = tid; b < 257; b += 256) hist[b] = 0;
            __syncthreads();
            for (int i = tid; i < n; i += 256)
                if ((!state || state[i] == want) && skey[i] == thr)
                    atomicAdd(&hist[i >> 5], 1u);
            __syncthreads();
            if (tid < 64) {
                uint32_t h0=hist[4*lane], h1=hist[4*lane+1], h2=hist[4*lane+2], h3=hist[4*lane+3];
                uint32_t T = h0+h1+h2+h3, I = T;
                for (int off = 1; off < 64; off <<= 1) {
                    uint32_t v = __shfl_up(I, off);
                    if (lane >= off) I += v;
                }
                uint32_t S = I - T;
                uint32_t a0=S+h0, a1=a0+h1, a2=a1+h2, a3=a2+h3;
                hist[4*lane]=a0; hist[4*lane+1]=a1; hist[4*lane+2]=a2; hist[4*lane+3]=a3;
            }
            __syncthreads();
            if (hist[tid] >= needS && (tid == 0 || hist[tid-1] < needS)) sh[1] = tid;
            __syncthreads();
            Bi = (uint32_t)sh[1];
            tie = true;
            __syncthreads();
            break;
        }
        prefix = thr; above = nAbove;
        if (shift == 21) { shift = 10; width = 11; mask = 0x7FFu; }
        else             { shift = 0;  width = 10; mask = 0x3FFu; }
        __syncthreads();
    }

    if (!tie && above == 0) {
        // fast path: bin-ordered compaction + same-bin ranking
        for (int b = tid; b < 2048; b += 256) binFill[b] = 0;
        __syncthreads();
        for (int i = tid; i < n; i += 256) {
            if (!state || state[i] == want) {
                uint32_t k = skey[i];
                if ((k >> shift) >= thr) {
                    uint32_t be = (k >> shift) & mask;
                    uint32_t pos = hist[be+1] + atomicAdd(&binFill[be], 1u);
                    cand[pos] = ((uint64_t)k << 32) | (uint32_t)(0xFFFFFFFFu - (uint32_t)i);
                }
            }
        }
        __syncthreads();
        int m = (int)hist[thr & mask];      // = suffix(B) since above==0
        for (int s = tid; s < m; s += 256) {
            uint64_t e = cand[s];
            uint32_t k = (uint32_t)(e >> 32);
            uint32_t be = (k >> shift) & mask;
            uint32_t base = hist[be+1];
            uint32_t cnt = hist[be] - base;
            uint32_t r = base;
            for (uint32_t s2 = base; s2 < base + cnt; ++s2)
                r += (cand[s2] > e) ? 1u : 0u;
            if (r < (uint32_t)t) outbuf[r] = e;
        }
        __syncthreads();
    } else {
        // general path: unordered compaction + full ranking
        if (tid == 0) sh[2] = 0;
        __syncthreads();
        for (int i0 = 0; i0 < n; i0 += 256) {
            int i = i0 + tid;
            bool take = false; uint32_t k = 0;
            if (i < n && (!state || state[i] == want)) {
                k = skey[i];
                take = tie ? (k > thr || (k == thr && (uint32_t)(i >> 5) <= Bi))
                           : ((k >> shift) >= thr);
            }
            unsigned long long mm = __ballot(take);
            if (mm) {
                int leader = __ffsll((long long)mm) - 1;
                int wbase = 0;
                if (lane == leader) wbase = atomicAdd(&sh[2], (int)__popcll(mm));
                wbase = __shfl(wbase, leader);
                if (take) {
                    int pos = wbase + __popcll(mm & ((1ull << lane) - 1ull));
                    cand[pos] = ((uint64_t)k << 32) | (uint32_t)(0xFFFFFFFFu - (uint32_t)i);
                }
            }
        }
        __syncthreads();
        int m = sh[2];
        for (int s = tid; s < m; s += 256) {
            uint64_t e = cand[s];
            uint32_t r = 0;
            for (int s2 = 0; s2 < m; ++s2) r += (cand[s2] > e) ? 1u : 0u;
            if (r < (uint32_t)t) outbuf[r] = e;
        }
        __syncthreads();
    }
}

// shared-memory layout (~55.7 KB)
#define SM_A      0        // class: skey 8000 | state @8000 | sdeg @10048; tail fallback: gkey 32000
#define SM_HIST   32000    // 2052*4 = 8208 (uses [0..2048])
#define SM_BINF   40208    // 2048*4 = 8192
#define SM_CAND   48400    // 768*8 = 6144
#define SM_OUT    54544    // 304*8 = 2432
#define SM_SH     56976    // 32
#define SM_BYTES  57008

// one block per class: sparse fixpoint NMS (== greedy), radix-select top-100,
// contribute to global clamped histogram; last block runs the cheap tail.
__global__ __launch_bounds__(256) void nms_class_kernel(float* __restrict__ out) {
    __shared__ __align__(16) char smem[SM_BYTES];
    uint32_t* skey  = (uint32_t*)(smem + SM_A);
    unsigned char* state = (unsigned char*)(smem + SM_A + 8000);
    uint16_t* sdeg  = (uint16_t*)(smem + SM_A + 10048);
    uint32_t* hist  = (uint32_t*)(smem + SM_HIST);
    uint32_t* binF  = (uint32_t*)(smem + SM_BINF);
    uint64_t* cand  = (uint64_t*)(smem + SM_CAND);
    uint64_t* outbuf= (uint64_t*)(smem + SM_OUT);
    int* sh         = (int*)(smem + SM_SH);
    __shared__ int s_ch[3];
    __shared__ int s_kept;
    const int c = blockIdx.x, tid = threadIdx.x;

    // coalesced score load from transposed layout
    {
        const float4* srow = (const float4*)&g_scoresT[c * N_PROP];
        for (int q = tid; q < N_PROP/4; q += 256) {
            float4 v = srow[q];
            skey[4*q+0] = fkey(v.x);
            skey[4*q+1] = fkey(v.y);
            skey[4*q+2] = fkey(v.z);
            skey[4*q+3] = fkey(v.w);
        }
    }
    for (int i = tid; i < N_PROP; i += 256) {
        int d = g_deg[i];
        sdeg[i] = (uint16_t)d;
        state[i] = (d == 0) ? ST_KEPT : ST_UNDEC;
    }
    if (tid < 3) s_ch[tid] = 0;
    __syncthreads();

    // fixpoint: keep[i] <=> no adjacent better j with keep[j]  (== greedy NMS)
    // 1 barrier/round via rotating 3-flag convergence check; state races are
    // benign (monotone lattice, unique fixpoint, flips are stable).
    int p = 0;
    for (;;) {
        s_ch[(p+2) % 3] = 0;    // clear flag two rounds ahead (race-safe)
        for (int i = tid; i < N_PROP; i += 256) {
            if (state[i] != ST_UNDEC) continue;
            uint32_t ki = skey[i];
            int deg = sdeg[i];
            bool anyKept = false, anyUndec = false;
            if (deg <= MAXNB) {
                for (int nn = 0; nn < deg; ++nn) {
                    int j = g_nbr[i * MAXNB + nn];
                    uint32_t kj = skey[j];
                    if (kj > ki || (kj == ki && j < i)) {
                        unsigned char stj = state[j];
                        if (stj == ST_KEPT) anyKept = true;
                        else if (stj == ST_UNDEC) anyUndec = true;
                    }
                }
            } else {
                for (int w = 0; w < 64; ++w) {
                    uint32_t bits = g_adj[i * 64 + w];
                    while (bits) {
                        int b = __ffs(bits) - 1; bits &= bits - 1;
                        int j = w * 32 + b;
                        uint32_t kj = skey[j];
                        if (kj > ki || (kj == ki && j < i)) {
                            unsigned char stj = state[j];
                            if (stj == ST_KEPT) anyKept = true;
                            else if (stj == ST_UNDEC) anyUndec = true;
                        }
                    }
                }
            }
            if (anyKept)        { state[i] = ST_SUPP; s_ch[p] = 1; }
            else if (!anyUndec) { state[i] = ST_KEPT; s_ch[p] = 1; }
        }
        __syncthreads();
        if (!s_ch[p]) break;
        p = (p + 1) % 3;
    }

    if (tid == 0) s_kept = 0;
    __syncthreads();
    {
        int local = 0;
        for (int i = tid; i < N_PROP; i += 256) local += (state[i] == ST_KEPT) ? 1 : 0;
        if (local) atomicAdd(&s_kept, local);
    }
    __syncthreads();
    const int kept = s_kept;

    const int t1 = kept < MAXPC ? kept : MAXPC;     // kept >= 1 always
    select_topt(skey, state, ST_KEPT, N_PROP, t1, hist, binF, cand, outbuf, sh);
    for (int r = tid; r < t1; r += 256) {
        uint64_t e = outbuf[r];
        g_outkey[c * MAXPC + r] = (uint32_t)(e >> 32);
        g_outidx[c * MAXPC + r] = (int)(0xFFFFFFFFu - (uint32_t)e);
    }
    if (kept < MAXPC) {
        __syncthreads();
        const int t2 = MAXPC - kept;                // suppressed count >= t2
        select_topt(skey, state, ST_SUPP, N_PROP, t2, hist, binF, cand, outbuf, sh);
        for (int r = tid; r < t2; r += 256) {
            uint64_t e = outbuf[r];
            g_outkey[c * MAXPC + kept + r] = FKEY_NEGINF;
            g_outidx[c * MAXPC + kept + r] = (int)(0xFFFFFFFFu - (uint32_t)e);
        }
    }
    __syncthreads();

    // contribute this class's 100 keys to the global clamped histogram
    for (int r = tid; r < MAXPC; r += 256)
        atomicAdd(&g_ghist[cbin(g_outkey[c * MAXPC + r])], 1u);

    // ---- fan-in: last block to finish runs the cheap global top-300 tail ----
    __threadfence();                                // release outkey/outidx/ghist
    if (tid == 0) sh[3] = atomicAdd(&g_done, 1);
    __syncthreads();
    if (sh[3] != NCLS - 1) return;
    __threadfence();                                // acquire others' writes

    // load precomputed global histogram, suffix-scan it in-block
    for (int b = tid; b <= 2048; b += 256) hist[b] = (b < 2048) ? g_ghist[b] : 0u;
    __syncthreads();
    {
        uint32_t c8 = 0;
        #pragma unroll 8
        for (int q = 0; q < 8; ++q) c8 += hist[tid*8 + q];
        binF[tid] = c8;
        __syncthreads();
        const int lane = tid & 63;
        if (tid < 64) {
            uint32_t h0=binF[4*lane], h1=binF[4*lane+1], h2=binF[4*lane+2], h3=binF[4*lane+3];
            uint32_t T = h0+h1+h2+h3, I = T;
            for (int off = 1; off < 64; off <<= 1) {
                uint32_t v = __shfl_down(I, off);
                if (lane + off < 64) I += v;
            }
            uint32_t S = I - T;
            uint32_t o3=h3+S, o2=h2+o3, o1=h1+o2, o0=h0+o1;
            binF[4*lane]=o0; binF[4*lane+1]=o1; binF[4*lane+2]=o2; binF[4*lane+3]=o3;
        }
        __syncthreads();
        uint32_t run = (tid == 255) ? 0u : binF[tid+1];
        uint32_t t7,t6,t5,t4,t3,t2,t1,t0;
        run += hist[tid*8+7]; t7 = run;
        run += hist[tid*8+6]; t6 = run;
        run += hist[tid*8+5]; t5 = run;
        run += hist[tid*8+4]; t4 = run;
        run += hist[tid*8+3]; t3 = run;
        run += hist[tid*8+2]; t2 = run;
        run += hist[tid*8+1]; t1 = run;
        run += hist[tid*8+0]; t0 = run;
        hist[tid*8+0]=t0; hist[tid*8+1]=t1; hist[tid*8+2]=t2; hist[tid*8+3]=t3;
        hist[tid*8+4]=t4; hist[tid*8+5]=t5; hist[tid*8+6]=t6; hist[tid*8+7]=t7;
        __syncthreads();
    }
    #pragma unroll 8
    for (int q = 0; q < 8; ++q) {
        int b = tid*8 + q;
        if (hist[b] >= (uint32_t)MAXIMG && hist[b+1] < (uint32_t)MAXIMG) sh[1] = b;
    }
    __syncthreads();
    const int B = sh[1];
    const uint32_t nCand = hist[B];

    if (B >= 1 && nCand <= CAP) {
        // fast tail: one filtered pass + per-bin ranking
        for (int b = tid; b < 2048; b += 256) binF[b] = 0;
        __syncthreads();
        for (int f = tid; f < NFLAT; f += 256) {
            uint32_t k = g_outkey[f];
            uint32_t be = cbin(k);
            if (be >= (uint32_t)B) {
                uint32_t pos = hist[be+1] + atomicAdd(&binF[be], 1u);
                cand[pos] = ((uint64_t)k << 32) | (uint32_t)(0xFFFFFFFFu - (uint32_t)f);
            }
        }
        __syncthreads();
        for (int s = tid; s < (int)nCand; s += 256) {
            uint64_t e = cand[s];
            uint32_t be = cbin((uint32_t)(e >> 32));
            uint32_t base = hist[be+1];
            uint32_t cnt2 = hist[be] - base;
            uint32_t r = base;
            for (uint32_t s2 = base; s2 < base + cnt2; ++s2)
                r += (cand[s2] > e) ? 1u : 0u;
            if (r < (uint32_t)MAXIMG) outbuf[r] = e;
        }
        __syncthreads();
    } else {
        // fallback: full in-block select over all 8000 keys
        uint32_t* gkey = (uint32_t*)(smem + SM_A);
        const uint4* gk4 = (const uint4*)g_outkey;
        uint4* lk4 = (uint4*)gkey;
        for (int q = tid; q < NFLAT/4; q += 256) lk4[q] = gk4[q];
        __syncthreads();
        select_topt(gkey, nullptr, 0, NFLAT, MAXIMG, hist, binF, cand, outbuf, sh);
    }

    for (int r = tid; r < MAXIMG; r += 256) {
        uint64_t e = outbuf[r];
        int f = (int)(0xFFFFFFFFu - (uint32_t)e);
        int pi = g_outidx[f];
        float4 b = g_boxes[pi];
        out[r*4+0] = b.x;
        out[r*4+1] = b.y;
        out[r*4+2] = b.z;
        out[r*4+3] = b.w;
        out[MAXIMG*4 + r] = (float)(f / MAXPC);
    }
}

extern "C" void kernel_launch(void* const* d_in, const int* in_sizes, int n_in,
                              void* d_out, int out_size, void* d_ws, size_t ws_size,
                              hipStream_t stream) {
    const float* deltas = (const float*)d_in[0];   // roi_bboxes_txtytwth [2000,4]
    const float* scores = (const float*)d_in[1];   // roi_score [2000,80]
    const float* props  = (const float*)d_in[2];   // rpn_proposals_bboxes [2000,4]
    float* out = (float*)d_out;                    // 1200 box floats + 300 class floats

    adj_kernel<<<N_PROP/4, 256, 0, stream>>>(deltas, props, scores);
    nms_class_kernel<<<NCLS, 256, 0, stream>>>(out);
}

// Round 7
// 70.806 us; speedup vs baseline: 1.3460x; 1.2267x over previous
//
#include <hip/hip_runtime.h>
#include <stdint.h>

#define N_PROP 2000
#define NCLS 80
#define MAXPC 100
#define MAXIMG 300
#define NFLAT (NCLS*MAXPC)   // 8000
#define MAXNB 32
#define CAP 768
#define FKEY_NEGINF 0x007FFFFFu

#define ST_UNDEC 0
#define ST_KEPT 1
#define ST_SUPP 2

// persistent device scratch (fully rewritten every launch -> deterministic)
__device__ float4   g_boxes[N_PROP];
__device__ uint32_t g_adj[N_PROP * 64];     // bitset rows (self-bit excluded)
__device__ int      g_deg[N_PROP];
__device__ int      g_nbr[N_PROP * MAXNB];  // neighbor lists (valid when deg<=MAXNB)
__device__ __align__(16) uint32_t g_outkey[NFLAT];
__device__ int      g_outidx[NFLAT];
__device__ __align__(16) float g_scoresT[NCLS * N_PROP];       // transposed scores
__device__ __align__(16) unsigned char g_state[NCLS * N_PROP]; // fixpoint result
__device__ uint32_t g_ghist[2048];          // global clamped-bin histogram

// monotone map: float -> uint32 such that u(a) < u(b) <=> a < b
__device__ __forceinline__ uint32_t fkey(float f) {
    uint32_t u = __float_as_uint(f);
    return (u & 0x80000000u) ? ~u : (u | 0x80000000u);
}

// fixed monotone clamped binning for the global-top-300 histogram:
// 2048 bins of width 2^12 over [fkey(0.5), fkey(1.0)) = [0xBF000000, 0xBF800000)
__device__ __forceinline__ uint32_t cbin(uint32_t k) {
    if (k < 0xBF000000u) return 0u;
    uint32_t b = (k - 0xBF000000u) >> 12;
    return b > 2047u ? 2047u : b;
}

// 500 blocks x 256: inline-decode all boxes to LDS, wave-per-row IoU bits,
// score transpose, ghist zero. Block 0 persists g_boxes.
__global__ __launch_bounds__(256) void adj_kernel(const float* __restrict__ deltas,
                                                  const float* __restrict__ props,
                                                  const float* __restrict__ scores) {
    __shared__ float4 bb[N_PROP];           // 32 KB
    const int tid = threadIdx.x;
    const float4* p4 = (const float4*)props;
    const float4* d4 = (const float4*)deltas;
    for (int i = tid; i < N_PROP; i += 256) {
        float4 p = p4[i], d = d4[i];
        float w = p.z - p.x + 1.0f, h = p.w - p.y + 1.0f;
        float cx = p.x + 0.5f*w,  cy = p.y + 0.5f*h;
        float pcx = d.x*w + cx, pcy = d.y*h + cy;
        float pw = expf(d.z)*w, ph = expf(d.w)*h;
        bb[i] = make_float4(pcx - 0.5f*pw, pcy - 0.5f*ph, pcx + 0.5f*pw, pcy + 0.5f*ph);
    }
    // coalesced-read score transpose: flat = i*80+c -> g_scoresT[c*2000+i]
    {
        int base = blockIdx.x * 320;
        for (int q = tid; q < 320; q += 256) {
            int flat = base + q;
            float v = scores[flat];
            g_scoresT[(flat % NCLS) * N_PROP + (flat / NCLS)] = v;
        }
    }
    if (blockIdx.x < 8) {
        int z = blockIdx.x * 256 + tid;
        if (z < 2048) g_ghist[z] = 0u;
    }
    __syncthreads();
    if (blockIdx.x == 0) {
        for (int i = tid; i < N_PROP; i += 256) g_boxes[i] = bb[i];
    }
    const int row = blockIdx.x * 4 + (tid >> 6);
    const int lane = tid & 63;
    float4 bi = bb[row];
    float ai = fmaxf(bi.z - bi.x, 0.0f) * fmaxf(bi.w - bi.y, 0.0f);
    uint32_t bits = 0u;
    #pragma unroll 8
    for (int b = 0; b < 32; ++b) {
        int j = lane * 32 + b;
        if (j < N_PROP && j != row) {
            float4 bj = bb[j];
            float aj = fmaxf(bj.z - bj.x, 0.0f) * fmaxf(bj.w - bj.y, 0.0f);
            float ix1 = fmaxf(bi.x, bj.x);
            float iy1 = fmaxf(bi.y, bj.y);
            float ix2 = fminf(bi.z, bj.z);
            float iy2 = fminf(bi.w, bj.w);
            float inter = fmaxf(ix2 - ix1, 0.0f) * fmaxf(iy2 - iy1, 0.0f);
            float uni = ai + aj - inter;
            if (inter > 0.7f * uni) bits |= (1u << b);
        }
    }
    g_adj[row * 64 + lane] = bits;
    // deterministic neighbor-list fill: wave prefix scan of popcounts
    int cnt = __popc(bits);
    int incl = cnt;
    for (int off = 1; off < 64; off <<= 1) {
        int v = __shfl_up(incl, off);
        if (lane >= off) incl += v;
    }
    int base = incl - cnt;
    if (lane == 63) g_deg[row] = incl;
    uint32_t t = bits; int k = 0;
    while (t) {
        int b = __ffs(t) - 1; t &= t - 1;
        int s = base + k; ++k;
        if (s < MAXNB) g_nbr[row * MAXNB + s] = lane * 32 + b;
    }
}

// one block per class: sparse fixpoint NMS (== greedy); writes g_state.
__global__ __launch_bounds__(256) void fix_kernel() {
    __shared__ uint32_t skey[N_PROP];
    __shared__ unsigned char state[N_PROP + 16];
    __shared__ uint16_t sdeg[N_PROP];
    __shared__ int s_ch[3];
    const int c = blockIdx.x, tid = threadIdx.x;

    {
        const float4* srow = (const float4*)&g_scoresT[c * N_PROP];
        #pragma unroll 2
        for (int q = tid; q < N_PROP/4; q += 256) {
            float4 v = srow[q];
            skey[4*q+0] = fkey(v.x);
            skey[4*q+1] = fkey(v.y);
            skey[4*q+2] = fkey(v.z);
            skey[4*q+3] = fkey(v.w);
        }
    }
    {
        const int4* dg4 = (const int4*)g_deg;
        #pragma unroll 2
        for (int q = tid; q < N_PROP/4; q += 256) {
            int4 d = dg4[q];
            sdeg[4*q+0] = (uint16_t)d.x; state[4*q+0] = d.x ? ST_UNDEC : ST_KEPT;
            sdeg[4*q+1] = (uint16_t)d.y; state[4*q+1] = d.y ? ST_UNDEC : ST_KEPT;
            sdeg[4*q+2] = (uint16_t)d.z; state[4*q+2] = d.z ? ST_UNDEC : ST_KEPT;
            sdeg[4*q+3] = (uint16_t)d.w; state[4*q+3] = d.w ? ST_UNDEC : ST_KEPT;
        }
    }
    if (tid < 3) s_ch[tid] = 0;
    __syncthreads();

    // fixpoint: keep[i] <=> no adjacent better j with keep[j]  (== greedy NMS)
    int p = 0;
    for (;;) {
        s_ch[(p+2) % 3] = 0;
        for (int i = tid; i < N_PROP; i += 256) {
            if (state[i] != ST_UNDEC) continue;
            uint32_t ki = skey[i];
            int deg = sdeg[i];
            bool anyKept = false, anyUndec = false;
            if (deg <= MAXNB) {
                for (int nn = 0; nn < deg; ++nn) {
                    int j = g_nbr[i * MAXNB + nn];
                    uint32_t kj = skey[j];
                    if (kj > ki || (kj == ki && j < i)) {
                        unsigned char stj = state[j];
                        if (stj == ST_KEPT) anyKept = true;
                        else if (stj == ST_UNDEC) anyUndec = true;
                    }
                }
            } else {
                for (int w = 0; w < 64; ++w) {
                    uint32_t bits = g_adj[i * 64 + w];
                    while (bits) {
                        int b = __ffs(bits) - 1; bits &= bits - 1;
                        int j = w * 32 + b;
                        uint32_t kj = skey[j];
                        if (kj > ki || (kj == ki && j < i)) {
                            unsigned char stj = state[j];
                            if (stj == ST_KEPT) anyKept = true;
                            else if (stj == ST_UNDEC) anyUndec = true;
                        }
                    }
                }
            }
            if (anyKept)        { state[i] = ST_SUPP; s_ch[p] = 1; }
            else if (!anyUndec) { state[i] = ST_KEPT; s_ch[p] = 1; }
        }
        __syncthreads();
        if (!s_ch[p]) break;
        p = (p + 1) % 3;
    }
    // packed u8 -> u32 store (500 words)
    uint32_t* gs = (uint32_t*)&g_state[c * N_PROP];
    const uint32_t* ls = (const uint32_t*)state;
    #pragma unroll 2
    for (int q = tid; q < N_PROP/4; q += 256) gs[q] = ls[q];
}

// Block-cooperative select (unchanged logic from round 5/6 — proven correct)
__device__ void select_topt(const uint32_t* __restrict__ skey,
                            const unsigned char* state, int want,
                            int n, int t,
                            uint32_t* hist,     // [>=2049]
                            uint32_t* binFill,  // [2048]
                            uint64_t* cand,     // [CAP]
                            uint64_t* outbuf,   // [>= t]
                            int* sh) {
    const int tid = threadIdx.x;
    const int lane = tid & 63;
    uint32_t prefix = 0, above = 0, thr = 0, Bi = 0, mask = 0x7FFu;
    int shift = 21, width = 11;
    bool tie = false;
    for (;;) {
        for (int b = tid; b <= 2048; b += 256) hist[b] = 0;
        __syncthreads();
        for (int i0 = 0; i0 < n; i0 += 256) {
            int i = i0 + tid;
            bool valid = false; uint32_t b = 0;
            if (i < n && (!state || state[i] == want)) {
                uint32_t k = skey[i];
                if (shift == 21 || (k >> (shift + width)) == prefix) {
                    valid = true; b = (k >> shift) & mask;
                }
            }
            uint32_t b0 = __shfl(b, 0);
            bool same = valid && (b == b0);
            unsigned long long eq = __ballot(same);
            if (eq == ~0ull) {
                if (lane == 0) atomicAdd(&hist[b0], 64u);
            } else if (valid) {
                atomicAdd(&hist[b], 1u);
            }
        }
        __syncthreads();
        {
            uint32_t c8 = 0;
            #pragma unroll 8
            for (int q = 0; q < 8; ++q) c8 += hist[tid*8 + q];
            binFill[tid] = c8;
            __syncthreads();
            if (tid < 64) {
                uint32_t h0=binFill[4*lane], h1=binFill[4*lane+1], h2=binFill[4*lane+2], h3=binFill[4*lane+3];
                uint32_t T = h0+h1+h2+h3, I = T;
                for (int off = 1; off < 64; off <<= 1) {
                    uint32_t v = __shfl_down(I, off);
                    if (lane + off < 64) I += v;
                }
                uint32_t S = I - T;
                uint32_t o3=h3+S, o2=h2+o3, o1=h1+o2, o0=h0+o1;
                binFill[4*lane]=o0; binFill[4*lane+1]=o1; binFill[4*lane+2]=o2; binFill[4*lane+3]=o3;
            }
            __syncthreads();
            uint32_t run = (tid == 255) ? 0u : binFill[tid+1];
            uint32_t t7,t6,t5,t4,t3,t2,t1,t0;
            run += hist[tid*8+7]; t7 = run;
            run += hist[tid*8+6]; t6 = run;
            run += hist[tid*8+5]; t5 = run;
            run += hist[tid*8+4]; t4 = run;
            run += hist[tid*8+3]; t3 = run;
            run += hist[tid*8+2]; t2 = run;
            run += hist[tid*8+1]; t1 = run;
            run += hist[tid*8+0]; t0 = run;
            hist[tid*8+0]=t0; hist[tid*8+1]=t1; hist[tid*8+2]=t2; hist[tid*8+3]=t3;
            hist[tid*8+4]=t4; hist[tid*8+5]=t5; hist[tid*8+6]=t6; hist[tid*8+7]=t7;
            __syncthreads();
        }
        #pragma unroll 8
        for (int q = 0; q < 8; ++q) {
            int b = tid*8 + q;
            uint32_t sb = hist[b], sb1 = hist[b+1];
            if (above + sb >= (uint32_t)t && above + sb1 < (uint32_t)t) sh[1] = b;
        }
        __syncthreads();
        int B = sh[1];
        uint32_t nCand = above + hist[B];
        uint32_t nAbove = above + hist[B+1];
        thr = (prefix << width) | (uint32_t)B;
        if (nCand <= CAP) { __syncthreads(); break; }
        if (shift == 0) {
            uint32_t needS = (uint32_t)t - nAbove;      // >= 1
            __syncthreads();
            for (int b = tid; b < 257; b += 256) hist[b] = 0;
            __syncthreads();
            for (int i = tid; i < n; i += 256)
                if ((!state || state[i] == want) && skey[i] == thr)
                    atomicAdd(&hist[i >> 5], 1u);
            __syncthreads();
            if (tid < 64) {
                uint32_t h0=hist[4*lane], h1=hist[4*lane+1], h2=hist[4*lane+2], h3=hist[4*lane+3];
                uint32_t T = h0+h1+h2+h3, I = T;
                for (int off = 1; off < 64; off <<= 1) {
                    uint32_t v = __shfl_up(I, off);
                    if (lane >= off) I += v;
                }
                uint32_t S = I - T;
                uint32_t a0=S+h0, a1=a0+h1, a2=a1+h2, a3=a2+h3;
                hist[4*lane]=a0; hist[4*lane+1]=a1; hist[4*lane+2]=a2; hist[4*lane+3]=a3;
            }
            __syncthreads();
            if (hist[tid] >= needS && (tid == 0 || hist[tid-1] < needS)) sh[1] = tid;
            __syncthreads();
            Bi = (uint32_t)sh[1];
            tie = true;
            __syncthreads();
            break;
        }
        prefix = thr; above = nAbove;
        if (shift == 21) { shift = 10; width = 11; mask = 0x7FFu; }
        else             { shift = 0;  width = 10; mask = 0x3FFu; }
        __syncthreads();
    }

    if (!tie && above == 0) {
        for (int b = tid; b < 2048; b += 256) binFill[b] = 0;
        __syncthreads();
        for (int i = tid; i < n; i += 256) {
            if (!state || state[i] == want) {
                uint32_t k = skey[i];
                if ((k >> shift) >= thr) {
                    uint32_t be = (k >> shift) & mask;
                    uint32_t pos = hist[be+1] + atomicAdd(&binFill[be], 1u);
                    cand[pos] = ((uint64_t)k << 32) | (uint32_t)(0xFFFFFFFFu - (uint32_t)i);
                }
            }
        }
        __syncthreads();
        int m = (int)hist[thr & mask];
        for (int s = tid; s < m; s += 256) {
            uint64_t e = cand[s];
            uint32_t k = (uint32_t)(e >> 32);
            uint32_t be = (k >> shift) & mask;
            uint32_t base = hist[be+1];
            uint32_t cnt = hist[be] - base;
            uint32_t r = base;
            #pragma unroll 4
            for (uint32_t s2 = base; s2 < base + cnt; ++s2)
                r += (cand[s2] > e) ? 1u : 0u;
            if (r < (uint32_t)t) outbuf[r] = e;
        }
        __syncthreads();
    } else {
        if (tid == 0) sh[2] = 0;
        __syncthreads();
        for (int i0 = 0; i0 < n; i0 += 256) {
            int i = i0 + tid;
            bool take = false; uint32_t k = 0;
            if (i < n && (!state || state[i] == want)) {
                k = skey[i];
                take = tie ? (k > thr || (k == thr && (uint32_t)(i >> 5) <= Bi))
                           : ((k >> shift) >= thr);
            }
            unsigned long long mm = __ballot(take);
            if (mm) {
                int leader = __ffsll((long long)mm) - 1;
                int wbase = 0;
                if (lane == leader) wbase = atomicAdd(&sh[2], (int)__popcll(mm));
                wbase = __shfl(wbase, leader);
                if (take) {
                    int pos = wbase + __popcll(mm & ((1ull << lane) - 1ull));
                    cand[pos] = ((uint64_t)k << 32) | (uint32_t)(0xFFFFFFFFu - (uint32_t)i);
                }
            }
        }
        __syncthreads();
        int m = sh[2];
        for (int s = tid; s < m; s += 256) {
            uint64_t e = cand[s];
            uint32_t r = 0;
            #pragma unroll 4
            for (int s2 = 0; s2 < m; ++s2) r += (cand[s2] > e) ? 1u : 0u;
            if (r < (uint32_t)t) outbuf[r] = e;
        }
        __syncthreads();
    }
}

// one block per class: radix-select top-100 kept, write outkey/outidx + ghist
__global__ __launch_bounds__(256) void sel_kernel() {
    __shared__ uint32_t skey[N_PROP];
    __shared__ unsigned char state[N_PROP + 16];
    __shared__ uint32_t hist[2052];
    __shared__ uint32_t binF[2048];
    __shared__ uint64_t cand[CAP];
    __shared__ uint64_t outbuf[304];
    __shared__ int sh[8];
    __shared__ int s_kept;
    const int c = blockIdx.x, tid = threadIdx.x;

    {
        const float4* srow = (const float4*)&g_scoresT[c * N_PROP];
        const uint32_t* gs = (const uint32_t*)&g_state[c * N_PROP];
        uint32_t* ls = (uint32_t*)state;
        #pragma unroll 2
        for (int q = tid; q < N_PROP/4; q += 256) {
            float4 v = srow[q];
            skey[4*q+0] = fkey(v.x);
            skey[4*q+1] = fkey(v.y);
            skey[4*q+2] = fkey(v.z);
            skey[4*q+3] = fkey(v.w);
            ls[q] = gs[q];
        }
    }
    if (tid == 0) s_kept = 0;
    __syncthreads();
    {
        int local = 0;
        for (int i = tid; i < N_PROP; i += 256) local += (state[i] == ST_KEPT) ? 1 : 0;
        if (local) atomicAdd(&s_kept, local);
    }
    __syncthreads();
    const int kept = s_kept;

    const int t1 = kept < MAXPC ? kept : MAXPC;     // kept >= 1 always
    select_topt(skey, state, ST_KEPT, N_PROP, t1, hist, binF, cand, outbuf, sh);
    for (int r = tid; r < t1; r += 256) {
        uint64_t e = outbuf[r];
        uint32_t k = (uint32_t)(e >> 32);
        g_outkey[c * MAXPC + r] = k;
        g_outidx[c * MAXPC + r] = (int)(0xFFFFFFFFu - (uint32_t)e);
        atomicAdd(&g_ghist[cbin(k)], 1u);
    }
    if (kept < MAXPC) {
        __syncthreads();
        const int t2 = MAXPC - kept;
        select_topt(skey, state, ST_SUPP, N_PROP, t2, hist, binF, cand, outbuf, sh);
        for (int r = tid; r < t2; r += 256) {
            uint64_t e = outbuf[r];
            g_outkey[c * MAXPC + kept + r] = FKEY_NEGINF;
            g_outidx[c * MAXPC + kept + r] = (int)(0xFFFFFFFFu - (uint32_t)e);
            atomicAdd(&g_ghist[cbin(FKEY_NEGINF)], 1u);
        }
    }
}

// single block: global top-300 via precomputed ghist + gather
#define SM_A      0        // fallback gkey 32000
#define SM_HIST   32000    // 2052*4
#define SM_BINF   40208    // 2048*4
#define SM_CAND   48400    // 768*8
#define SM_OUT    54544    // 304*8
#define SM_SH     56976
#define SM_BYTES  57008

__global__ __launch_bounds__(256) void tail_kernel(float* __restrict__ out) {
    __shared__ __align__(16) char smem[SM_BYTES];
    uint32_t* hist  = (uint32_t*)(smem + SM_HIST);
    uint32_t* binF  = (uint32_t*)(smem + SM_BINF);
    uint64_t* cand  = (uint64_t*)(smem + SM_CAND);
    uint64_t* outbuf= (uint64_t*)(smem + SM_OUT);
    int* sh         = (int*)(smem + SM_SH);
    const int tid = threadIdx.x;
    const int lane = tid & 63;

    for (int b = tid; b <= 2048; b += 256) hist[b] = (b < 2048) ? g_ghist[b] : 0u;
    __syncthreads();
    {
        uint32_t c8 = 0;
        #pragma unroll 8
        for (int q = 0; q < 8; ++q) c8 += hist[tid*8 + q];
        binF[tid] = c8;
        __syncthreads();
        if (tid < 64) {
            uint32_t h0=binF[4*lane], h1=binF[4*lane+1], h2=binF[4*lane+2], h3=binF[4*lane+3];
            uint32_t T = h0+h1+h2+h3, I = T;
            for (int off = 1; off < 64; off <<= 1) {
                uint32_t v = __shfl_down(I, off);
                if (lane + off < 64) I += v;
            }
            uint32_t S = I - T;
            uint32_t o3=h3+S, o2=h2+o3, o1=h1+o2, o0=h0+o1;
            binF[4*lane]=o0; binF[4*lane+1]=o1; binF[4*lane+2]=o2; binF[4*lane+3]=o3;
        }
        __syncthreads();
        uint32_t run = (tid == 255) ? 0u : binF[tid+1];
        uint32_t t7,t6,t5,t4,t3,t2,t1,t0;
        run += hist[tid*8+7]; t7 = run;
        run += hist[tid*8+6]; t6 = run;
        run += hist[tid*8+5]; t5 = run;
        run += hist[tid*8+4]; t4 = run;
        run += hist[tid*8+3]; t3 = run;
        run += hist[tid*8+2]; t2 = run;
        run += hist[tid*8+1]; t1 = run;
        run += hist[tid*8+0]; t0 = run;
        hist[tid*8+0]=t0; hist[tid*8+1]=t1; hist[tid*8+2]=t2; hist[tid*8+3]=t3;
        hist[tid*8+4]=t4; hist[tid*8+5]=t5; hist[tid*8+6]=t6; hist[tid*8+7]=t7;
        __syncthreads();
    }
    #pragma unroll 8
    for (int q = 0; q < 8; ++q) {
        int b = tid*8 + q;
        if (hist[b] >= (uint32_t)MAXIMG && hist[b+1] < (uint32_t)MAXIMG) sh[1] = b;
    }
    __syncthreads();
    const int B = sh[1];
    const uint32_t nCand = hist[B];

    if (B >= 1 && nCand <= CAP) {
        for (int b = tid; b < 2048; b += 256) binF[b] = 0;
        __syncthreads();
        const uint4* ok4 = (const uint4*)g_outkey;
        for (int q = tid; q < NFLAT/4; q += 256) {
            uint4 kv = ok4[q];
            #pragma unroll
            for (int j = 0; j < 4; ++j) {
                uint32_t k = (&kv.x)[j];
                uint32_t be = cbin(k);
                if (be >= (uint32_t)B) {
                    uint32_t pos = hist[be+1] + atomicAdd(&binF[be], 1u);
                    cand[pos] = ((uint64_t)k << 32) | (uint32_t)(0xFFFFFFFFu - (uint32_t)(q*4+j));
                }
            }
        }
        __syncthreads();
        for (int s = tid; s < (int)nCand; s += 256) {
            uint64_t e = cand[s];
            uint32_t be = cbin((uint32_t)(e >> 32));
            uint32_t base = hist[be+1];
            uint32_t cnt2 = hist[be] - base;
            uint32_t r = base;
            #pragma unroll 4
            for (uint32_t s2 = base; s2 < base + cnt2; ++s2)
                r += (cand[s2] > e) ? 1u : 0u;
            if (r < (uint32_t)MAXIMG) outbuf[r] = e;
        }
        __syncthreads();
    } else {
        uint32_t* gkey = (uint32_t*)(smem + SM_A);
        const uint4* gk4 = (const uint4*)g_outkey;
        uint4* lk4 = (uint4*)gkey;
        for (int q = tid; q < NFLAT/4; q += 256) lk4[q] = gk4[q];
        __syncthreads();
        select_topt(gkey, nullptr, 0, NFLAT, MAXIMG, hist, binF, cand, outbuf, sh);
    }

    for (int r = tid; r < MAXIMG; r += 256) {
        uint64_t e = outbuf[r];
        int f = (int)(0xFFFFFFFFu - (uint32_t)e);
        int pi = g_outidx[f];
        float4 b = g_boxes[pi];
        out[r*4+0] = b.x;
        out[r*4+1] = b.y;
        out[r*4+2] = b.z;
        out[r*4+3] = b.w;
        out[MAXIMG*4 + r] = (float)(f / MAXPC);
    }
}

extern "C" void kernel_launch(void* const* d_in, const int* in_sizes, int n_in,
                              void* d_out, int out_size, void* d_ws, size_t ws_size,
                              hipStream_t stream) {
    const float* deltas = (const float*)d_in[0];   // roi_bboxes_txtytwth [2000,4]
    const float* scores = (const float*)d_in[1];   // roi_score [2000,80]
    const float* props  = (const float*)d_in[2];   // rpn_proposals_bboxes [2000,4]
    float* out = (float*)d_out;                    // 1200 box floats + 300 class floats

    adj_kernel<<<N_PROP/4, 256, 0, stream>>>(deltas, props, scores);
    fix_kernel<<<NCLS, 256, 0, stream>>>();
    sel_kernel<<<NCLS, 256, 0, stream>>>();
    tail_kernel<<<1, 256, 0, stream>>>(out);
}

// Round 8
// 53.326 us; speedup vs baseline: 1.7872x; 1.3278x over previous
//
#include <hip/hip_runtime.h>
#include <stdint.h>

#define N_PROP 2000
#define NCLS 80
#define MAXPC 100
#define MAXIMG 300
#define NFLAT (NCLS*MAXPC)   // 8000
#define MAXNB 32
#define CAP 768
#define FKEY_NEGINF 0x007FFFFFu

#define ST_UNDEC 0
#define ST_KEPT 1
#define ST_SUPP 2

// persistent device scratch (fully rewritten every launch -> deterministic)
__device__ float4   g_boxes[N_PROP];
__device__ uint32_t g_adj[N_PROP * 64];     // bitset rows (self-bit excluded)
__device__ int      g_deg[N_PROP];
__device__ int      g_nbr[N_PROP * MAXNB];  // neighbor lists (valid when deg<=MAXNB)
__device__ __align__(16) uint32_t g_outkey[NFLAT];
__device__ int      g_outidx[NFLAT];
__device__ __align__(16) float g_scoresT[NCLS * N_PROP];  // transposed scores
__device__ uint32_t g_ghist[2048];          // global clamped-bin histogram

// monotone map: float -> uint32 such that u(a) < u(b) <=> a < b
__device__ __forceinline__ uint32_t fkey(float f) {
    uint32_t u = __float_as_uint(f);
    return (u & 0x80000000u) ? ~u : (u | 0x80000000u);
}

// fixed monotone clamped binning for the global-top-300 histogram:
// 2048 bins of width 2^12 over [fkey(0.5), fkey(1.0)) = [0xBF000000, 0xBF800000)
__device__ __forceinline__ uint32_t cbin(uint32_t k) {
    if (k < 0xBF000000u) return 0u;
    uint32_t b = (k - 0xBF000000u) >> 12;
    return b > 2047u ? 2047u : b;
}

// 125 blocks x 1024: inline-decode all boxes to LDS, wave-per-row IoU bits
// (16 rows/block), score transpose, ghist zero. Block 0 persists g_boxes.
__global__ __launch_bounds__(1024) void adj_kernel(const float* __restrict__ deltas,
                                                   const float* __restrict__ props,
                                                   const float* __restrict__ scores) {
    __shared__ float4 bb[N_PROP];           // 32 KB
    const int tid = threadIdx.x;
    const float4* p4 = (const float4*)props;
    const float4* d4 = (const float4*)deltas;
    for (int i = tid; i < N_PROP; i += 1024) {
        float4 p = p4[i], d = d4[i];
        float w = p.z - p.x + 1.0f, h = p.w - p.y + 1.0f;
        float cx = p.x + 0.5f*w,  cy = p.y + 0.5f*h;
        float pcx = d.x*w + cx, pcy = d.y*h + cy;
        float pw = expf(d.z)*w, ph = expf(d.w)*h;
        bb[i] = make_float4(pcx - 0.5f*pw, pcy - 0.5f*ph, pcx + 0.5f*pw, pcy + 0.5f*ph);
    }
    // coalesced-read score transpose: flat = i*80+c -> g_scoresT[c*2000+i]
    {
        int base = blockIdx.x * 1280;       // 125 * 1280 = 160000
        for (int q = tid; q < 1280; q += 1024) {
            int flat = base + q;
            float v = scores[flat];
            g_scoresT[(flat % NCLS) * N_PROP + (flat / NCLS)] = v;
        }
    }
    if (blockIdx.x < 2) {
        int z = blockIdx.x * 1024 + tid;
        g_ghist[z] = 0u;
    }
    __syncthreads();
    if (blockIdx.x == 0) {
        for (int i = tid; i < N_PROP; i += 1024) g_boxes[i] = bb[i];
    }
    const int row = blockIdx.x * 16 + (tid >> 6);
    const int lane = tid & 63;
    float4 bi = bb[row];
    float ai = fmaxf(bi.z - bi.x, 0.0f) * fmaxf(bi.w - bi.y, 0.0f);
    uint32_t bits = 0u;
    #pragma unroll 8
    for (int b = 0; b < 32; ++b) {
        int j = lane * 32 + b;
        if (j < N_PROP && j != row) {
            float4 bj = bb[j];
            float aj = fmaxf(bj.z - bj.x, 0.0f) * fmaxf(bj.w - bj.y, 0.0f);
            float ix1 = fmaxf(bi.x, bj.x);
            float iy1 = fmaxf(bi.y, bj.y);
            float ix2 = fminf(bi.z, bj.z);
            float iy2 = fminf(bi.w, bj.w);
            float inter = fmaxf(ix2 - ix1, 0.0f) * fmaxf(iy2 - iy1, 0.0f);
            float uni = ai + aj - inter;
            if (inter > 0.7f * uni) bits |= (1u << b);
        }
    }
    g_adj[row * 64 + lane] = bits;
    // deterministic neighbor-list fill: wave prefix scan of popcounts
    int cnt = __popc(bits);
    int incl = cnt;
    for (int off = 1; off < 64; off <<= 1) {
        int v = __shfl_up(incl, off);
        if (lane >= off) incl += v;
    }
    int base = incl - cnt;
    if (lane == 63) g_deg[row] = incl;
    uint32_t t = bits; int k = 0;
    while (t) {
        int b = __ffs(t) - 1; t &= t - 1;
        int s = base + k; ++k;
        if (s < MAXNB) g_nbr[row * MAXNB + s] = lane * 32 + b;
    }
}

// Block-cooperative select, 1024 threads. Among {i: !state || state[i]==want},
// top-t by (skey desc, idx asc), SORTED into outbuf[0..t-1] as
// (key<<32)|(0xFFFFFFFF-i). Requires 1 <= t <= min(count(valid),300), n<=8192.
__device__ void select_topt(const uint32_t* __restrict__ skey,
                            const unsigned char* state, int want,
                            int n, int t,
                            uint32_t* hist,     // [>=2049]
                            uint32_t* binFill,  // [2048]
                            uint64_t* cand,     // [CAP]
                            uint64_t* outbuf,   // [>= t]
                            int* sh) {
    const int tid = threadIdx.x;
    const int lane = tid & 63;
    uint32_t prefix = 0, above = 0, thr = 0, Bi = 0, mask = 0x7FFu;
    int shift = 21, width = 11;
    bool tie = false;
    for (;;) {
        for (int b = tid; b <= 2048; b += 1024) hist[b] = 0;
        __syncthreads();
        for (int i0 = 0; i0 < n; i0 += 1024) {
            int i = i0 + tid;
            bool valid = false; uint32_t b = 0;
            if (i < n && (!state || state[i] == want)) {
                uint32_t k = skey[i];
                if (shift == 21 || (k >> (shift + width)) == prefix) {
                    valid = true; b = (k >> shift) & mask;
                }
            }
            uint32_t b0 = __shfl(b, 0);
            bool same = valid && (b == b0);
            unsigned long long eq = __ballot(same);
            if (eq == ~0ull) {
                if (lane == 0) atomicAdd(&hist[b0], 64u);
            } else if (valid) {
                atomicAdd(&hist[b], 1u);
            }
        }
        __syncthreads();
        // suffix scan: hist[b] <- count(valid, bin >= b); hist[2048] stays 0
        if (tid < 256) {
            uint32_t c8 = 0;
            #pragma unroll 8
            for (int q = 0; q < 8; ++q) c8 += hist[tid*8 + q];
            binFill[tid] = c8;
        }
        __syncthreads();
        if (tid < 64) {
            uint32_t h0=binFill[4*lane], h1=binFill[4*lane+1], h2=binFill[4*lane+2], h3=binFill[4*lane+3];
            uint32_t T = h0+h1+h2+h3, I = T;
            for (int off = 1; off < 64; off <<= 1) {
                uint32_t v = __shfl_down(I, off);
                if (lane + off < 64) I += v;
            }
            uint32_t S = I - T;
            uint32_t o3=h3+S, o2=h2+o3, o1=h1+o2, o0=h0+o1;
            binFill[4*lane]=o0; binFill[4*lane+1]=o1; binFill[4*lane+2]=o2; binFill[4*lane+3]=o3;
        }
        __syncthreads();
        if (tid < 256) {
            uint32_t run = (tid == 255) ? 0u : binFill[tid+1];
            uint32_t t7,t6,t5,t4,t3,t2,t1,t0;
            run += hist[tid*8+7]; t7 = run;
            run += hist[tid*8+6]; t6 = run;
            run += hist[tid*8+5]; t5 = run;
            run += hist[tid*8+4]; t4 = run;
            run += hist[tid*8+3]; t3 = run;
            run += hist[tid*8+2]; t2 = run;
            run += hist[tid*8+1]; t1 = run;
            run += hist[tid*8+0]; t0 = run;
            hist[tid*8+0]=t0; hist[tid*8+1]=t1; hist[tid*8+2]=t2; hist[tid*8+3]=t3;
            hist[tid*8+4]=t4; hist[tid*8+5]=t5; hist[tid*8+6]=t6; hist[tid*8+7]=t7;
        }
        __syncthreads();
        if (tid < 256) {
            #pragma unroll 8
            for (int q = 0; q < 8; ++q) {
                int b = tid*8 + q;
                uint32_t sb = hist[b], sb1 = hist[b+1];
                if (above + sb >= (uint32_t)t && above + sb1 < (uint32_t)t) sh[1] = b;
            }
        }
        __syncthreads();
        int B = sh[1];
        uint32_t nCand = above + hist[B];
        uint32_t nAbove = above + hist[B+1];
        thr = (prefix << width) | (uint32_t)B;
        if (nCand <= CAP) { __syncthreads(); break; }
        if (shift == 0) {
            // mass exact-key ties at thr: take smallest indices (32-idx word cut)
            uint32_t needS = (uint32_t)t - nAbove;      // >= 1
            __syncthreads();
            for (int b = tid; b < 257; b += 1024) hist[b] = 0;
            __syncthreads();
            for (int i = tid; i < n; i += 1024)
                if ((!state || state[i] == want) && skey[i] == thr)
                    atomicAdd(&hist[i >> 5], 1u);
            __syncthreads();
            if (tid < 64) {     // ascending inclusive scan of hist[0..255]
                uint32_t h0=hist[4*lane], h1=hist[4*lane+1], h2=hist[4*lane+2], h3=hist[4*lane+3];
                uint32_t T = h0+h1+h2+h3, I = T;
                for (int off = 1; off < 64; off <<= 1) {
                    uint32_t v = __shfl_up(I, off);
                    if (lane >= off) I += v;
                }
                uint32_t S = I - T;
                uint32_t a0=S+h0, a1=a0+h1, a2=a1+h2, a3=a2+h3;
                hist[4*lane]=a0; hist[4*lane+1]=a1; hist[4*lane+2]=a2; hist[4*lane+3]=a3;
            }
            __syncthreads();
            if (tid < 256) {
                if (hist[tid] >= needS && (tid == 0 || hist[tid-1] < needS)) sh[1] = tid;
            }
            __syncthreads();
            Bi = (uint32_t)sh[1];
            tie = true;
            __syncthreads();
            break;
        }
        prefix = thr; above = nAbove;
        if (shift == 21) { shift = 10; width = 11; mask = 0x7FFu; }
        else             { shift = 0;  width = 10; mask = 0x3FFu; }
        __syncthreads();
    }

    if (!tie && above == 0) {
        // fast path: bin-ordered compaction + same-bin ranking
        for (int b = tid; b < 2048; b += 1024) binFill[b] = 0;
        __syncthreads();
        for (int i = tid; i < n; i += 1024) {
            if (!state || state[i] == want) {
                uint32_t k = skey[i];
                if ((k >> shift) >= thr) {
                    uint32_t be = (k >> shift) & mask;
                    uint32_t pos = hist[be+1] + atomicAdd(&binFill[be], 1u);
                    cand[pos] = ((uint64_t)k << 32) | (uint32_t)(0xFFFFFFFFu - (uint32_t)i);
                }
            }
        }
        __syncthreads();
        int m = (int)hist[thr & mask];
        for (int s = tid; s < m; s += 1024) {
            uint64_t e = cand[s];
            uint32_t k = (uint32_t)(e >> 32);
            uint32_t be = (k >> shift) & mask;
            uint32_t base = hist[be+1];
            uint32_t cnt = hist[be] - base;
            uint32_t r = base;
            #pragma unroll 4
            for (uint32_t s2 = base; s2 < base + cnt; ++s2)
                r += (cand[s2] > e) ? 1u : 0u;
            if (r < (uint32_t)t) outbuf[r] = e;
        }
        __syncthreads();
    } else {
        // general path: unordered compaction + full ranking
        if (tid == 0) sh[2] = 0;
        __syncthreads();
        for (int i0 = 0; i0 < n; i0 += 1024) {
            int i = i0 + tid;
            bool take = false; uint32_t k = 0;
            if (i < n && (!state || state[i] == want)) {
                k = skey[i];
                take = tie ? (k > thr || (k == thr && (uint32_t)(i >> 5) <= Bi))
                           : ((k >> shift) >= thr);
            }
            unsigned long long mm = __ballot(take);
            if (mm) {
                int leader = __ffsll((long long)mm) - 1;
                int wbase = 0;
                if (lane == leader) wbase = atomicAdd(&sh[2], (int)__popcll(mm));
                wbase = __shfl(wbase, leader);
                if (take) {
                    int pos = wbase + __popcll(mm & ((1ull << lane) - 1ull));
                    cand[pos] = ((uint64_t)k << 32) | (uint32_t)(0xFFFFFFFFu - (uint32_t)i);
                }
            }
        }
        __syncthreads();
        int m = sh[2];
        for (int s = tid; s < m; s += 1024) {
            uint64_t e = cand[s];
            uint32_t r = 0;
            #pragma unroll 4
            for (int s2 = 0; s2 < m; ++s2) r += (cand[s2] > e) ? 1u : 0u;
            if (r < (uint32_t)t) outbuf[r] = e;
        }
        __syncthreads();
    }
}

// one block per class, 1024 threads: fixpoint NMS (== greedy) + top-100 select
__global__ __launch_bounds__(1024) void fixsel_kernel() {
    __shared__ uint32_t skey[N_PROP];
    __shared__ unsigned char state[N_PROP + 16];
    __shared__ uint16_t sdeg[N_PROP];
    __shared__ uint32_t hist[2052];
    __shared__ uint32_t binF[2048];
    __shared__ uint64_t cand[CAP];
    __shared__ uint64_t outbuf[304];
    __shared__ int sh[8];
    __shared__ int s_ch[3];
    __shared__ int s_kept;
    const int c = blockIdx.x, tid = threadIdx.x;

    // single-iteration loads: 500 float4 / 500 int4
    if (tid < 500) {
        const float4* srow = (const float4*)&g_scoresT[c * N_PROP];
        float4 v = srow[tid];
        skey[4*tid+0] = fkey(v.x);
        skey[4*tid+1] = fkey(v.y);
        skey[4*tid+2] = fkey(v.z);
        skey[4*tid+3] = fkey(v.w);
        int4 d = ((const int4*)g_deg)[tid];
        sdeg[4*tid+0] = (uint16_t)d.x; state[4*tid+0] = d.x ? ST_UNDEC : ST_KEPT;
        sdeg[4*tid+1] = (uint16_t)d.y; state[4*tid+1] = d.y ? ST_UNDEC : ST_KEPT;
        sdeg[4*tid+2] = (uint16_t)d.z; state[4*tid+2] = d.z ? ST_UNDEC : ST_KEPT;
        sdeg[4*tid+3] = (uint16_t)d.w; state[4*tid+3] = d.w ? ST_UNDEC : ST_KEPT;
    }
    if (tid < 3) s_ch[tid] = 0;
    __syncthreads();

    // fixpoint: keep[i] <=> no adjacent better j with keep[j]  (== greedy NMS)
    // one barrier/round; clear flag for round p+1 during round p (race-free:
    // f_{p+1}'s writers/readers are separated from this clear by the round-p
    // barrier; the old (p+2)%3 variant aliased round p-1's flag concurrently
    // with its break-read).
    int p = 0;
    for (;;) {
        s_ch[(p+1) % 3] = 0;
        for (int i = tid; i < N_PROP; i += 1024) {
            if (state[i] != ST_UNDEC) continue;
            uint32_t ki = skey[i];
            int deg = sdeg[i];
            bool anyKept = false, anyUndec = false;
            if (deg <= MAXNB) {
                for (int nn = 0; nn < deg; ++nn) {
                    int j = g_nbr[i * MAXNB + nn];
                    uint32_t kj = skey[j];
                    if (kj > ki || (kj == ki && j < i)) {
                        unsigned char stj = state[j];
                        if (stj == ST_KEPT) anyKept = true;
                        else if (stj == ST_UNDEC) anyUndec = true;
                    }
                }
            } else {
                for (int w = 0; w < 64; ++w) {
                    uint32_t bits = g_adj[i * 64 + w];
                    while (bits) {
                        int b = __ffs(bits) - 1; bits &= bits - 1;
                        int j = w * 32 + b;
                        uint32_t kj = skey[j];
                        if (kj > ki || (kj == ki && j < i)) {
                            unsigned char stj = state[j];
                            if (stj == ST_KEPT) anyKept = true;
                            else if (stj == ST_UNDEC) anyUndec = true;
                        }
                    }
                }
            }
            if (anyKept)        { state[i] = ST_SUPP; s_ch[p] = 1; }
            else if (!anyUndec) { state[i] = ST_KEPT; s_ch[p] = 1; }
        }
        __syncthreads();
        if (!s_ch[p]) break;
        p = (p + 1) % 3;
    }

    if (tid == 0) s_kept = 0;
    __syncthreads();
    {
        int local = 0;
        for (int i = tid; i < N_PROP; i += 1024) local += (state[i] == ST_KEPT) ? 1 : 0;
        if (local) atomicAdd(&s_kept, local);
    }
    __syncthreads();
    const int kept = s_kept;

    const int t1 = kept < MAXPC ? kept : MAXPC;     // kept >= 1 always
    select_topt(skey, state, ST_KEPT, N_PROP, t1, hist, binF, cand, outbuf, sh);
    for (int r = tid; r < t1; r += 1024) {
        uint64_t e = outbuf[r];
        uint32_t k = (uint32_t)(e >> 32);
        g_outkey[c * MAXPC + r] = k;
        g_outidx[c * MAXPC + r] = (int)(0xFFFFFFFFu - (uint32_t)e);
        atomicAdd(&g_ghist[cbin(k)], 1u);
    }
    if (kept < MAXPC) {
        __syncthreads();
        const int t2 = MAXPC - kept;                // suppressed count >= t2
        select_topt(skey, state, ST_SUPP, N_PROP, t2, hist, binF, cand, outbuf, sh);
        for (int r = tid; r < t2; r += 1024) {
            uint64_t e = outbuf[r];
            g_outkey[c * MAXPC + kept + r] = FKEY_NEGINF;
            g_outidx[c * MAXPC + kept + r] = (int)(0xFFFFFFFFu - (uint32_t)e);
            atomicAdd(&g_ghist[cbin(FKEY_NEGINF)], 1u);
        }
    }
}

// single block, 1024 threads: global top-300 via precomputed ghist + gather
#define SM_A      0        // fallback gkey 32000
#define SM_HIST   32000    // 2052*4
#define SM_BINF   40208    // 2048*4
#define SM_CAND   48400    // 768*8
#define SM_OUT    54544    // 304*8
#define SM_SH     56976
#define SM_BYTES  57008

__global__ __launch_bounds__(1024) void tail_kernel(float* __restrict__ out) {
    __shared__ __align__(16) char smem[SM_BYTES];
    uint32_t* hist  = (uint32_t*)(smem + SM_HIST);
    uint32_t* binF  = (uint32_t*)(smem + SM_BINF);
    uint64_t* cand  = (uint64_t*)(smem + SM_CAND);
    uint64_t* outbuf= (uint64_t*)(smem + SM_OUT);
    int* sh         = (int*)(smem + SM_SH);
    const int tid = threadIdx.x;
    const int lane = tid & 63;

    for (int b = tid; b <= 2048; b += 1024) hist[b] = (b < 2048) ? g_ghist[b] : 0u;
    __syncthreads();
    if (tid < 256) {
        uint32_t c8 = 0;
        #pragma unroll 8
        for (int q = 0; q < 8; ++q) c8 += hist[tid*8 + q];
        binF[tid] = c8;
    }
    __syncthreads();
    if (tid < 64) {
        uint32_t h0=binF[4*lane], h1=binF[4*lane+1], h2=binF[4*lane+2], h3=binF[4*lane+3];
        uint32_t T = h0+h1+h2+h3, I = T;
        for (int off = 1; off < 64; off <<= 1) {
            uint32_t v = __shfl_down(I, off);
            if (lane + off < 64) I += v;
        }
        uint32_t S = I - T;
        uint32_t o3=h3+S, o2=h2+o3, o1=h1+o2, o0=h0+o1;
        binF[4*lane]=o0; binF[4*lane+1]=o1; binF[4*lane+2]=o2; binF[4*lane+3]=o3;
    }
    __syncthreads();
    if (tid < 256) {
        uint32_t run = (tid == 255) ? 0u : binF[tid+1];
        uint32_t t7,t6,t5,t4,t3,t2,t1,t0;
        run += hist[tid*8+7]; t7 = run;
        run += hist[tid*8+6]; t6 = run;
        run += hist[tid*8+5]; t5 = run;
        run += hist[tid*8+4]; t4 = run;
        run += hist[tid*8+3]; t3 = run;
        run += hist[tid*8+2]; t2 = run;
        run += hist[tid*8+1]; t1 = run;
        run += hist[tid*8+0]; t0 = run;
        hist[tid*8+0]=t0; hist[tid*8+1]=t1; hist[tid*8+2]=t2; hist[tid*8+3]=t3;
        hist[tid*8+4]=t4; hist[tid*8+5]=t5; hist[tid*8+6]=t6; hist[tid*8+7]=t7;
    }
    __syncthreads();
    if (tid < 256) {
        #pragma unroll 8
        for (int q = 0; q < 8; ++q) {
            int b = tid*8 + q;
            if (hist[b] >= (uint32_t)MAXIMG && hist[b+1] < (uint32_t)MAXIMG) sh[1] = b;
        }
    }
    __syncthreads();
    const int B = sh[1];
    const uint32_t nCand = hist[B];

    if (B >= 1 && nCand <= CAP) {
        for (int b = tid; b < 2048; b += 1024) binF[b] = 0;
        __syncthreads();
        const uint4* ok4 = (const uint4*)g_outkey;
        for (int q = tid; q < NFLAT/4; q += 1024) {
            uint4 kv = ok4[q];
            #pragma unroll
            for (int j = 0; j < 4; ++j) {
                uint32_t k = (&kv.x)[j];
                uint32_t be = cbin(k);
                if (be >= (uint32_t)B) {
                    uint32_t pos = hist[be+1] + atomicAdd(&binF[be], 1u);
                    cand[pos] = ((uint64_t)k << 32) | (uint32_t)(0xFFFFFFFFu - (uint32_t)(q*4+j));
                }
            }
        }
        __syncthreads();
        for (int s = tid; s < (int)nCand; s += 1024) {
            uint64_t e = cand[s];
            uint32_t be = cbin((uint32_t)(e >> 32));
            uint32_t base = hist[be+1];
            uint32_t cnt2 = hist[be] - base;
            uint32_t r = base;
            #pragma unroll 4
            for (uint32_t s2 = base; s2 < base + cnt2; ++s2)
                r += (cand[s2] > e) ? 1u : 0u;
            if (r < (uint32_t)MAXIMG) outbuf[r] = e;
        }
        __syncthreads();
    } else {
        uint32_t* gkey = (uint32_t*)(smem + SM_A);
        const uint4* gk4 = (const uint4*)g_outkey;
        uint4* lk4 = (uint4*)gkey;
        for (int q = tid; q < NFLAT/4; q += 1024) lk4[q] = gk4[q];
        __syncthreads();
        select_topt(gkey, nullptr, 0, NFLAT, MAXIMG, hist, binF, cand, outbuf, sh);
    }

    for (int r = tid; r < MAXIMG; r += 1024) {
        uint64_t e = outbuf[r];
        int f = (int)(0xFFFFFFFFu - (uint32_t)e);
        int pi = g_outidx[f];
        float4 b = g_boxes[pi];
        out[r*4+0] = b.x;
        out[r*4+1] = b.y;
        out[r*4+2] = b.z;
        out[r*4+3] = b.w;
        out[MAXIMG*4 + r] = (float)(f / MAXPC);
    }
}

extern "C" void kernel_launch(void* const* d_in, const int* in_sizes, int n_in,
                              void* d_out, int out_size, void* d_ws, size_t ws_size,
                              hipStream_t stream) {
    const float* deltas = (const float*)d_in[0];   // roi_bboxes_txtytwth [2000,4]
    const float* scores = (const float*)d_in[1];   // roi_score [2000,80]
    const float* props  = (const float*)d_in[2];   // rpn_proposals_bboxes [2000,4]
    float* out = (float*)d_out;                    // 1200 box floats + 300 class floats

    adj_kernel<<<125, 1024, 0, stream>>>(deltas, props, scores);
    fixsel_kernel<<<NCLS, 1024, 0, stream>>>();
    tail_kernel<<<1, 1024, 0, stream>>>(out);
}